// Round 9
// baseline (1199.781 us; speedup 1.0000x reference)
//
#include <hip/hip_runtime.h>
#include <stdint.h>

#define N_TOK   65536
#define MDIM    2048
#define FDIM    512
#define SCALE_F 10.0f
#define TAU_BF  1.2e-3f   // level-1: bf16-S ambiguity (~9 sigma)
#define TAU_SP  2e-5f     // level-2: split-S ambiguity (~100 sigma)
#define QCAP    8192

typedef __attribute__((ext_vector_type(8))) unsigned short u16x8;
typedef __attribute__((ext_vector_type(8))) __bf16 bf16x8;
typedef __attribute__((ext_vector_type(4))) float f32x4;

__device__ __forceinline__ unsigned short f2bf(float f) {
  unsigned int u = __builtin_bit_cast(unsigned int, f);
  u += 0x7fffu + ((u >> 16) & 1u);   // round-to-nearest-even
  return (unsigned short)(u >> 16);
}
__device__ __forceinline__ float bf2f(unsigned short b) {
  return __builtin_bit_cast(float, (unsigned int)b << 16);
}
__device__ __forceinline__ f32x4 mfma16(u16x8 a, u16x8 b, f32x4 c) {
  return __builtin_amdgcn_mfma_f32_16x16x32_bf16(
      __builtin_bit_cast(bf16x8, a), __builtin_bit_cast(bf16x8, b), c, 0, 0, 0);
}
__device__ __forceinline__ void gload16(const unsigned short* g, unsigned short* l) {
  __builtin_amdgcn_global_load_lds(
      (const __attribute__((address_space(1))) unsigned int*)g,
      (__attribute__((address_space(3))) unsigned int*)l,
      16, 0, 0);
}
// order-preserving float->u32 (handles negatives); tie -> smaller col wins max
__device__ __forceinline__ unsigned long long packkey(float x, int col) {
  unsigned u = __builtin_bit_cast(unsigned, x);
  u = (u & 0x80000000u) ? ~u : (u | 0x80000000u);
  return ((unsigned long long)u << 32) | (unsigned)(2048 - col);
}
__device__ __forceinline__ float unpackval(unsigned long long k) {
  unsigned u = (unsigned)(k >> 32);
  u = (u & 0x80000000u) ? (u & 0x7fffffffu) : ~u;
  return __builtin_bit_cast(float, u);
}
__device__ __forceinline__ int unpackcol(unsigned long long k) {
  return 2048 - (int)(k & 0xffffffffu);
}
// top-2 merge of two disjoint sorted pairs
__device__ __forceinline__ void merge2(unsigned long long& k1, unsigned long long& k2,
                                       unsigned long long o1, unsigned long long o2) {
  if (o1 > k1) { k2 = (k1 > o2) ? k1 : o2; k1 = o1; }
  else if (o1 > k2) { k2 = o1; }
}

// ---------------- zero queue counter ----------------
__global__ __launch_bounds__(64) void zero_k(int* __restrict__ qcount) {
  if (threadIdx.x == 0) *qcount = 0;
}

// ---------------- memory_norm -> bf16 hi/lo ----------------
__global__ __launch_bounds__(64) void prep_memory_k(
    const float* __restrict__ mem, unsigned short* __restrict__ Bh,
    unsigned short* __restrict__ Bl) {
  const int m = blockIdx.x;
  const int lane = threadIdx.x;
  const float* row = mem + (size_t)m * FDIM;
  float4 a = *(const float4*)(row + lane * 4);
  float4 b = *(const float4*)(row + 256 + lane * 4);
  float s = a.x * a.x + a.y * a.y + a.z * a.z + a.w * a.w +
            b.x * b.x + b.y * b.y + b.z * b.z + b.w * b.w;
  #pragma unroll
  for (int off = 1; off < 64; off <<= 1) s += __shfl_xor(s, off);
  const float rn = 1.0f / sqrtf(fmaxf(s, 1e-12f));
  float v[8] = {a.x, a.y, a.z, a.w, b.x, b.y, b.z, b.w};
  #pragma unroll
  for (int h = 0; h < 2; ++h) {
    ushort4 hs, lo;
    #pragma unroll
    for (int q = 0; q < 4; ++q) {
      float x = v[h * 4 + q] * rn;
      unsigned short hb = f2bf(x);
      ((unsigned short*)&hs)[q] = hb;
      ((unsigned short*)&lo)[q] = f2bf(x - bf2f(hb));
    }
    const size_t e = (size_t)m * FDIM + h * 256 + lane * 4;
    *(ushort4*)(Bh + e) = hs;
    *(ushort4*)(Bl + e) = lo;
  }
}

// ---------------- transpose Bh [M][F] -> Bt [F][M] ----------------
__global__ __launch_bounds__(256) void transpose_k(
    const unsigned short* __restrict__ Bh, unsigned short* __restrict__ Bt) {
  __shared__ unsigned short t[32][33];
  const int m0 = blockIdx.x * 32, f0 = blockIdx.y * 32;
  const int tx = threadIdx.x & 31, ty = threadIdx.x >> 5;
  #pragma unroll
  for (int r = ty; r < 32; r += 8)
    t[r][tx] = Bh[(size_t)(m0 + r) * FDIM + f0 + tx];
  __syncthreads();
  #pragma unroll
  for (int r = ty; r < 32; r += 8)
    Bt[(size_t)(f0 + r) * MDIM + m0 + tx] = t[tx][r];
}

// ---------------- input row inv-norms (f32) ----------------
__global__ __launch_bounds__(256) void input_norms_k(
    const float* __restrict__ inp, float* __restrict__ inv_n) {
  const int row = blockIdx.x * 4 + (threadIdx.x >> 6);
  const int lane = threadIdx.x & 63;
  const float* x = inp + (size_t)row * FDIM;
  float4 a = *(const float4*)(x + lane * 4);
  float4 b = *(const float4*)(x + 256 + lane * 4);
  float s = a.x * a.x + a.y * a.y + a.z * a.z + a.w * a.w +
            b.x * b.x + b.y * b.y + b.z * b.z + b.w * b.w;
  #pragma unroll
  for (int off = 1; off < 64; off <<= 1) s += __shfl_xor(s, off);
  if (lane == 0) inv_n[row] = 1.0f / sqrtf(fmaxf(s, 1e-12f));
}

// ---------------- inputs_norm chunk -> bf16 (hi only) ----------------
__global__ __launch_bounds__(256) void prep_a_k(
    const float* __restrict__ inp, const float* __restrict__ inv_n,
    unsigned short* __restrict__ Ah, int baseRow) {
  const size_t q4 = (size_t)blockIdx.x * 256 + threadIdx.x;
  const size_t e = q4 * 4;
  const int lrow = (int)(e >> 9);
  const float rn = inv_n[baseRow + lrow];
  float4 x = *(const float4*)(inp + (size_t)(baseRow + lrow) * FDIM + (e & 511));
  ushort4 hs;
  hs.x = f2bf(x.x * rn); hs.y = f2bf(x.y * rn);
  hs.z = f2bf(x.z * rn); hs.w = f2bf(x.w * rn);
  *(ushort4*)(Ah + e) = hs;
}

// ------------- GEMM: C = A * B^T (B row-major [N][K]), 128x128 tile -------------
// MODE 0: plain fp32 C.  MODE 1: P=bf16(exp(10*s)) + per-row sidecar partials
// (sum of exp + packed top-2 over this block's 128 cols).  MODE 2: fp32 C
// scaled by rowscale[row].  SPLIT (MODE 0 only): hi/lo bf16 compensation.
template <int MODE, bool SPLIT, bool SWZ>
__global__ __launch_bounds__(256) void gemm_bt_k(
    const unsigned short* __restrict__ Ah, const unsigned short* __restrict__ Al,
    const unsigned short* __restrict__ Bh, const unsigned short* __restrict__ Bl,
    void* __restrict__ Cv, int N, int K, int nbxLog2,
    const int* __restrict__ qlimit, float* __restrict__ ssum,
    unsigned long long* __restrict__ sk1, unsigned long long* __restrict__ sk2,
    const float* __restrict__ rowscale) {
  int wg = blockIdx.x;
  if (SWZ) {  // bijective: nwg % 8 == 0 guaranteed by launcher
    const int q = gridDim.x >> 3;
    wg = (wg & 7) * q + (wg >> 3);
  }
  const int bx = wg & ((1 << nbxLog2) - 1);
  const int by = wg >> nbxLog2;
  const int m0 = by * 128, n0 = bx * 128;
  if (qlimit) {
    int lim = *qlimit; if (lim > QCAP) lim = QCAP;
    lim = (lim + 127) & ~127;
    if (m0 >= lim) return;
  }
  __shared__ alignas(16) unsigned short sAh[128 * 32];
  __shared__ alignas(16) unsigned short sBh[128 * 32];
  __shared__ alignas(16) unsigned short sAl[SPLIT ? 128 * 32 : 8];
  __shared__ alignas(16) unsigned short sBl[SPLIT ? 128 * 32 : 8];

  const int tid = threadIdx.x;
  const int lane = tid & 63, wave = tid >> 6;
  const int wr = wave >> 1, wc = wave & 1;
  const int lr = lane & 15, ls = lane >> 4;

  f32x4 acc[4][4] = {};

  const int row0 = wave * 32 + (lane >> 2);
  const int row1 = row0 + 16;
  const int ce = (lane & 3) * 8;
  const unsigned short* gA0 = Ah + (size_t)(m0 + row0) * K + ce;
  const unsigned short* gA1 = Ah + (size_t)(m0 + row1) * K + ce;
  const unsigned short* gB0 = Bh + (size_t)(n0 + row0) * K + ce;
  const unsigned short* gB1 = Bh + (size_t)(n0 + row1) * K + ce;
  const unsigned short* gAl0 = nullptr; const unsigned short* gAl1 = nullptr;
  const unsigned short* gBl0 = nullptr; const unsigned short* gBl1 = nullptr;
  if constexpr (SPLIT) {
    gAl0 = Al + (size_t)(m0 + row0) * K + ce;
    gAl1 = Al + (size_t)(m0 + row1) * K + ce;
    gBl0 = Bl + (size_t)(n0 + row0) * K + ce;
    gBl1 = Bl + (size_t)(n0 + row1) * K + ce;
  }
  unsigned short* lA0 = &sAh[wave * 1024];
  unsigned short* lA1 = &sAh[wave * 1024 + 512];
  unsigned short* lB0 = &sBh[wave * 1024];
  unsigned short* lB1 = &sBh[wave * 1024 + 512];
  unsigned short* lAl0 = SPLIT ? &sAl[wave * 1024] : nullptr;
  unsigned short* lAl1 = SPLIT ? &sAl[wave * 1024 + 512] : nullptr;
  unsigned short* lBl0 = SPLIT ? &sBl[wave * 1024] : nullptr;
  unsigned short* lBl1 = SPLIT ? &sBl[wave * 1024 + 512] : nullptr;

  const int nk = K >> 5;
  for (int ks = 0; ks < nk; ++ks) {
    gload16(gA0, lA0); gload16(gA1, lA1);
    gload16(gB0, lB0); gload16(gB1, lB1);
    if constexpr (SPLIT) {
      gload16(gAl0, lAl0); gload16(gAl1, lAl1);
      gload16(gBl0, lBl0); gload16(gBl1, lBl1);
    }
    gA0 += 32; gA1 += 32; gB0 += 32; gB1 += 32;
    if constexpr (SPLIT) { gAl0 += 32; gAl1 += 32; gBl0 += 32; gBl1 += 32; }
    __syncthreads();

    u16x8 fa[4], fb[4], fal[4], fbl[4];
    #pragma unroll
    for (int i = 0; i < 4; ++i) {
      const int ra = (wr * 64 + i * 16 + lr) * 32 + ls * 8;
      const int rb = (wc * 64 + i * 16 + lr) * 32 + ls * 8;
      fa[i] = *(const u16x8*)&sAh[ra];
      fb[i] = *(const u16x8*)&sBh[rb];
      if constexpr (SPLIT) {
        fal[i] = *(const u16x8*)&sAl[ra];
        fbl[i] = *(const u16x8*)&sBl[rb];
      }
    }
    #pragma unroll
    for (int i = 0; i < 4; ++i)
      #pragma unroll
      for (int j = 0; j < 4; ++j) {
        acc[i][j] = mfma16(fa[i], fb[j], acc[i][j]);
        if constexpr (SPLIT) {
          acc[i][j] = mfma16(fal[i], fb[j], acc[i][j]);
          acc[i][j] = mfma16(fa[i], fbl[j], acc[i][j]);
        }
      }
    __syncthreads();
  }

  if constexpr (MODE == 1) {
    unsigned short* P = (unsigned short*)Cv;
    #pragma unroll
    for (int i = 0; i < 4; ++i) {
      #pragma unroll
      for (int q = 0; q < 4; ++q) {
        const int row = m0 + wr * 64 + i * 16 + ls * 4 + q;
        float sv[4];
        unsigned long long kk[4];
        float esum = 0.f;
        #pragma unroll
        for (int j = 0; j < 4; ++j) {
          const int col = n0 + wc * 64 + j * 16 + lr;
          sv[j] = acc[i][j][q];
          kk[j] = packkey(sv[j], col);
          const float e = __expf(SCALE_F * sv[j]);
          esum += e;
          P[(size_t)row * N + col] = f2bf(e);
        }
        // local top-2 of 4
        unsigned long long a = kk[0] > kk[1] ? kk[0] : kk[1];
        unsigned long long b = kk[0] > kk[1] ? kk[1] : kk[0];
        unsigned long long c = kk[2] > kk[3] ? kk[2] : kk[3];
        unsigned long long d = kk[2] > kk[3] ? kk[3] : kk[2];
        unsigned long long k1, k2;
        if (a > c) { k1 = a; k2 = (b > c) ? b : c; }
        else       { k1 = c; k2 = (d > a) ? d : a; }
        // butterfly over lr (lane bits 0..3)
        #pragma unroll
        for (int off = 1; off < 16; off <<= 1) {
          const unsigned long long o1 = __shfl_xor(k1, off);
          const unsigned long long o2 = __shfl_xor(k2, off);
          esum += __shfl_xor(esum, off);
          merge2(k1, k2, o1, o2);
        }
        if (lr == 0) {
          const size_t sp = (size_t)row * 32 + bx * 2 + wc;
          ssum[sp] = esum; sk1[sp] = k1; sk2[sp] = k2;
        }
      }
    }
  } else {
    float* C = (float*)Cv;
    #pragma unroll
    for (int i = 0; i < 4; ++i) {
      const int rrow = m0 + wr * 64 + i * 16 + ls * 4;
      #pragma unroll
      for (int j = 0; j < 4; ++j) {
        const int col = n0 + wc * 64 + j * 16 + lr;
        #pragma unroll
        for (int q = 0; q < 4; ++q) {
          float v = acc[i][j][q];
          if constexpr (MODE == 2) v *= rowscale[rrow + q];
          C[(size_t)(rrow + q) * N + col] = v;
        }
      }
    }
  }
}

// ------- merge 32 sidecar partials per row: idx, rowinv, queue -------
__global__ __launch_bounds__(256) void rowstat_k(
    const float* __restrict__ ssum, const unsigned long long* __restrict__ sk1,
    const unsigned long long* __restrict__ sk2, int* __restrict__ idx,
    float* __restrict__ rowinv, int* __restrict__ queue,
    int* __restrict__ qcount, int baseRow) {
  const int row = blockIdx.x * 8 + (threadIdx.x >> 5);
  const int p = threadIdx.x & 31;
  const size_t sp = (size_t)row * 32 + p;
  float sum = ssum[sp];
  unsigned long long k1 = sk1[sp], k2 = sk2[sp];
  #pragma unroll
  for (int off = 1; off < 32; off <<= 1) {
    const unsigned long long o1 = __shfl_xor(k1, off);
    const unsigned long long o2 = __shfl_xor(k2, off);
    sum += __shfl_xor(sum, off);
    merge2(k1, k2, o1, o2);
  }
  if (p == 0) {
    const int tok = baseRow + row;
    idx[tok] = unpackcol(k1);
    rowinv[row] = 1.0f / sum;
    if (unpackval(k1) - unpackval(k2) < TAU_BF) {
      int slot = atomicAdd(qcount, 1);
      if (slot < QCAP) queue[slot] = tok;
    }
  }
}

// ------- gather queued tokens' normalized rows -> compact hi/lo matrix -------
__global__ __launch_bounds__(256) void gather_prep_k(
    const int* __restrict__ queue, const int* __restrict__ qcount,
    const float* __restrict__ inp, const float* __restrict__ inv_n,
    unsigned short* __restrict__ Qh, unsigned short* __restrict__ Ql) {
  const int w = blockIdx.x * 4 + (threadIdx.x >> 6);
  const int lane = threadIdx.x & 63;
  int cnt = *qcount; if (cnt > QCAP) cnt = QCAP;
  if (w >= cnt) return;
  const int tok = queue[w];
  const float rn = inv_n[tok];
  const float* x = inp + (size_t)tok * FDIM;
  #pragma unroll
  for (int h = 0; h < 2; ++h) {
    float4 xv = *(const float4*)(x + h * 256 + lane * 4);
    float vv[4] = {xv.x, xv.y, xv.z, xv.w};
    ushort4 hs, lo;
    #pragma unroll
    for (int q = 0; q < 4; ++q) {
      float v = vv[q] * rn;
      unsigned short hb = f2bf(v);
      ((unsigned short*)&hs)[q] = hb;
      ((unsigned short*)&lo)[q] = f2bf(v - bf2f(hb));
    }
    const size_t e = (size_t)w * FDIM + h * 256 + lane * 4;
    *(ushort4*)(Qh + e) = hs;
    *(ushort4*)(Ql + e) = lo;
  }
}

// ------- level-2: full-row top-2 on split-S; fp64 pair-decide; write idx -------
__global__ __launch_bounds__(256) void refine2_k(
    const int* __restrict__ queue, const int* __restrict__ qcount,
    const float* __restrict__ Sref, const float* __restrict__ inp,
    const float* __restrict__ mem, int* __restrict__ idx) {
  const int w = blockIdx.x * 4 + (threadIdx.x >> 6);
  const int lane = threadIdx.x & 63;
  int cnt = *qcount; if (cnt > QCAP) cnt = QCAP;
  if (w >= cnt) return;
  const int tok = queue[w];
  const float* srow = Sref + (size_t)w * MDIM;
  float m1 = -3.4e38f, m2 = -3.4e38f;
  int i1 = 0x7fffffff, i2 = 0x7fffffff;
  #pragma unroll
  for (int i = 0; i < 8; ++i) {
    const float4 vv = *(const float4*)(srow + i * 256 + lane * 4);
    const float xs[4] = {vv.x, vv.y, vv.z, vv.w};
    #pragma unroll
    for (int q = 0; q < 4; ++q) {
      const float x = xs[q];
      const int ii = i * 256 + lane * 4 + q;
      if (x > m1 || (x == m1 && ii < i1)) { m2 = m1; i2 = i1; m1 = x; i1 = ii; }
      else if (x > m2 || (x == m2 && ii < i2)) { m2 = x; i2 = ii; }
    }
  }
  #pragma unroll
  for (int off = 1; off < 64; off <<= 1) {
    const float n1 = __shfl_xor(m1, off), n2 = __shfl_xor(m2, off);
    const int j1 = __shfl_xor(i1, off), j2 = __shfl_xor(i2, off);
    if (n1 > m1 || (n1 == m1 && j1 < i1)) {
      if (m1 > n2 || (m1 == n2 && i1 < j2)) { m2 = m1; i2 = i1; }
      else { m2 = n2; i2 = j2; }
      m1 = n1; i1 = j1;
    } else if (n1 > m2 || (n1 == m2 && j1 < i2)) { m2 = n1; i2 = j1; }
  }
  int pick = i1;
  if (m1 - m2 < TAU_SP) {  // near-tie even at split accuracy -> fp64 decides
    const int a = (i1 < i2) ? i1 : i2, b = (i1 < i2) ? i2 : i1;
    const float* x = inp + (size_t)tok * FDIM;
    const float* ma = mem + (size_t)a * FDIM;
    const float* mb = mem + (size_t)b * FDIM;
    double da = 0, db = 0, na = 0, nb = 0;
    #pragma unroll
    for (int j = 0; j < 8; ++j) {
      const int e = lane * 8 + j;
      const double xv = x[e], av = ma[e], bv = mb[e];
      da += xv * av; na += av * av;
      db += xv * bv; nb += bv * bv;
    }
    #pragma unroll
    for (int off = 1; off < 64; off <<= 1) {
      da += __shfl_xor(da, off); na += __shfl_xor(na, off);
      db += __shfl_xor(db, off); nb += __shfl_xor(nb, off);
    }
    const double d1 = da / sqrt(fmax(na, 1e-12));
    const double d2 = db / sqrt(fmax(nb, 1e-12));
    if (d2 > d1) pick = b;
    else pick = a;                      // includes exact tie: smaller index
  }
  if (lane == 0) idx[tok] = pick;
}

// ------- deterministic segment-sum: one block per code, no atomics -------
__global__ __launch_bounds__(256) void segsum_k(
    const int* __restrict__ idx, const float* __restrict__ inp,
    const float* __restrict__ inv_n, float* __restrict__ updates) {
  __shared__ int lst[256];
  __shared__ int lcnt;
  const int m = blockIdx.x;
  const int t = threadIdx.x;
  float a0 = 0.f, a1 = 0.f;
  for (int base = 0; base < N_TOK; base += 4096) {
    if (t == 0) lcnt = 0;
    __syncthreads();
    #pragma unroll
    for (int u = 0; u < 4; ++u) {
      const int off4 = (u * 256 + t) * 4;
      const int4 v = *(const int4*)&idx[base + off4];
      if (v.x == m) { int p = atomicAdd(&lcnt, 1); if (p < 256) lst[p] = base + off4 + 0; }
      if (v.y == m) { int p = atomicAdd(&lcnt, 1); if (p < 256) lst[p] = base + off4 + 1; }
      if (v.z == m) { int p = atomicAdd(&lcnt, 1); if (p < 256) lst[p] = base + off4 + 2; }
      if (v.w == m) { int p = atomicAdd(&lcnt, 1); if (p < 256) lst[p] = base + off4 + 3; }
    }
    __syncthreads();
    int c = lcnt; if (c > 256) c = 256;
    if (t == 0 && c > 1) {
      for (int i = 1; i < c; ++i) {
        int key = lst[i], j = i - 1;
        while (j >= 0 && lst[j] > key) { lst[j + 1] = lst[j]; --j; }
        lst[j + 1] = key;
      }
    }
    __syncthreads();
    for (int i = 0; i < c; ++i) {
      const int tok = lst[i];
      const float rn = inv_n[tok];
      const float2 xv = *(const float2*)&inp[(size_t)tok * FDIM + t * 2];
      a0 += xv.x * rn; a1 += xv.y * rn;
    }
    __syncthreads();
  }
  *(float2*)&updates[(size_t)m * FDIM + t * 2] = make_float2(a0, a1);
}

// ---------------- final blend (fp32 out) ----------------
__global__ __launch_bounds__(256) void final_update_k(
    const float* __restrict__ mem, const float* __restrict__ upd,
    float* __restrict__ out) {
  const size_t i = ((size_t)blockIdx.x * 256 + threadIdx.x) * 4;
  float4 m = *(const float4*)(mem + i);
  float4 u = *(const float4*)(upd + i);
  float4 r;
  r.x = m.x * 0.9f + u.x * 0.1f;
  r.y = m.y * 0.9f + u.y * 0.1f;
  r.z = m.z * 0.9f + u.z * 0.1f;
  r.w = m.w * 0.9f + u.w * 0.1f;
  *(float4*)(out + i) = r;
}

extern "C" void kernel_launch(void* const* d_in, const int* in_sizes, int n_in,
                              void* d_out, int out_size, void* d_ws, size_t ws_size,
                              hipStream_t stream) {
  const float* inputs = (const float*)d_in[0];
  const float* memory = (const float*)d_in[1];
  if (n_in >= 2 && in_sizes[0] != N_TOK * FDIM) {  // order guard
    inputs = (const float*)d_in[1];
    memory = (const float*)d_in[0];
  }
  float* out_mu = (float*)d_out;                       // [N][F] fp32
  float* out_um = out_mu + (size_t)N_TOK * FDIM;       // [M][F] fp32

  char* base = (char*)d_ws;
  size_t off = 0;
  auto take = [&](size_t bytes) -> char* {
    char* p = base + off;
    off = (off + bytes + 255) & ~(size_t)255;
    return p;
  };
  unsigned short* Bh = (unsigned short*)take((size_t)MDIM * FDIM * 2);
  unsigned short* Bl = (unsigned short*)take((size_t)MDIM * FDIM * 2);
  unsigned short* Bt = (unsigned short*)take((size_t)MDIM * FDIM * 2);
  float* inv_n = (float*)take((size_t)N_TOK * 4);
  float* updates = (float*)take((size_t)MDIM * FDIM * 4);
  int* idx = (int*)take((size_t)N_TOK * 4);
  int* queue = (int*)take((size_t)QCAP * 4);
  int* qcount = (int*)take(256);
  unsigned short* Qh = (unsigned short*)take((size_t)QCAP * FDIM * 2);
  unsigned short* Ql = (unsigned short*)take((size_t)QCAP * FDIM * 2);
  float* Sref = (float*)take((size_t)QCAP * MDIM * 4);
  const size_t fixed = off;

  // per-token: Ah 1024 + P 4096 + sidecar (32*(4+8+8))=640 + rowinv 4
  int chunkT = 32768;
  while (chunkT > 128 && fixed + (size_t)chunkT * 5764 + 8192 > ws_size)
    chunkT >>= 1;
  if (fixed + (size_t)chunkT * 5764 + 8192 > ws_size) return;  // ws too small

  unsigned short* Ah = (unsigned short*)take((size_t)chunkT * FDIM * 2);
  unsigned short* Pbuf = (unsigned short*)take((size_t)chunkT * MDIM * 2);
  float* ssum = (float*)take((size_t)chunkT * 32 * 4);
  unsigned long long* sk1 = (unsigned long long*)take((size_t)chunkT * 32 * 8);
  unsigned long long* sk2 = (unsigned long long*)take((size_t)chunkT * 32 * 8);
  float* rowinv = (float*)take((size_t)chunkT * 4);

  zero_k<<<1, 64, 0, stream>>>(qcount);
  prep_memory_k<<<MDIM, 64, 0, stream>>>(memory, Bh, Bl);
  transpose_k<<<dim3(MDIM / 32, FDIM / 32), 256, 0, stream>>>(Bh, Bt);
  input_norms_k<<<N_TOK / 4, 256, 0, stream>>>(inputs, inv_n);

  const int nby = chunkT / 128;
  for (int baseRow = 0; baseRow < N_TOK; baseRow += chunkT) {
    prep_a_k<<<chunkT / 2, 256, 0, stream>>>(inputs, inv_n, Ah, baseRow);
    // GEMM1 + exp + sidecar (S never hits HBM)
    gemm_bt_k<1, false, true><<<16 * nby, 256, 0, stream>>>(
        Ah, nullptr, Bh, nullptr, (void*)Pbuf, MDIM, FDIM, 4, nullptr,
        ssum, sk1, sk2, nullptr);
    rowstat_k<<<chunkT / 8, 256, 0, stream>>>(
        ssum, sk1, sk2, idx, rowinv, queue, qcount, baseRow);
    // GEMM2: out = (P * Bt^T) * rowinv
    gemm_bt_k<2, false, true><<<4 * nby, 256, 0, stream>>>(
        Pbuf, nullptr, Bt, nullptr, (void*)(out_mu + (size_t)baseRow * FDIM),
        FDIM, MDIM, 2, nullptr, nullptr, nullptr, nullptr, rowinv);
  }
  // two-level argmax refine: gather ambiguous rows, split-GEMM, decide idx
  gather_prep_k<<<QCAP / 4, 256, 0, stream>>>(queue, qcount, inputs, inv_n, Qh, Ql);
  gemm_bt_k<0, true, false><<<16 * (QCAP / 128), 256, 0, stream>>>(
      Qh, Ql, Bh, Bl, (void*)Sref, MDIM, FDIM, 4, qcount,
      nullptr, nullptr, nullptr, nullptr);
  refine2_k<<<QCAP / 4, 256, 0, stream>>>(queue, qcount, Sref, inputs, memory, idx);
  // deterministic segment-sum (no atomics), then blend
  segsum_k<<<MDIM, 256, 0, stream>>>(idx, inputs, inv_n, updates);
  final_update_k<<<(MDIM * FDIM / 4) / 256, 256, 0, stream>>>(memory, updates, out_um);
}

// Round 10
// 874.594 us; speedup vs baseline: 1.3718x; 1.3718x over previous
//
#include <hip/hip_runtime.h>
#include <stdint.h>

#define N_TOK   65536
#define MDIM    2048
#define FDIM    512
#define SCALE_F 10.0f
#define TAU_BF  1.2e-3f   // level-1: bf16-S ambiguity (~9 sigma)
#define TAU_SP  2e-5f     // level-2: split-S ambiguity (~100 sigma)
#define QCAP    8192

typedef __attribute__((ext_vector_type(8))) unsigned short u16x8;
typedef __attribute__((ext_vector_type(4))) unsigned short u16x4;
typedef __attribute__((ext_vector_type(8))) __bf16 bf16x8;
typedef __attribute__((ext_vector_type(4))) float f32x4;

__device__ __forceinline__ unsigned short f2bf(float f) {
  unsigned int u = __builtin_bit_cast(unsigned int, f);
  u += 0x7fffu + ((u >> 16) & 1u);   // round-to-nearest-even
  return (unsigned short)(u >> 16);
}
__device__ __forceinline__ float bf2f(unsigned short b) {
  return __builtin_bit_cast(float, (unsigned int)b << 16);
}
__device__ __forceinline__ f32x4 mfma16(u16x8 a, u16x8 b, f32x4 c) {
  return __builtin_amdgcn_mfma_f32_16x16x32_bf16(
      __builtin_bit_cast(bf16x8, a), __builtin_bit_cast(bf16x8, b), c, 0, 0, 0);
}
__device__ __forceinline__ void gload16(const unsigned short* g, unsigned short* l) {
  __builtin_amdgcn_global_load_lds(
      (const __attribute__((address_space(1))) unsigned int*)g,
      (__attribute__((address_space(3))) unsigned int*)l,
      16, 0, 0);
}
// order-preserving float->u32; tie -> smaller col wins (np.argmax)
__device__ __forceinline__ unsigned long long packkey(float x, int col) {
  unsigned u = __builtin_bit_cast(unsigned, x);
  u = (u & 0x80000000u) ? ~u : (u | 0x80000000u);
  return ((unsigned long long)u << 32) | (unsigned)(2048 - col);
}
__device__ __forceinline__ float unpackval(unsigned long long k) {
  unsigned u = (unsigned)(k >> 32);
  u = (u & 0x80000000u) ? (u & 0x7fffffffu) : ~u;
  return __builtin_bit_cast(float, u);
}
__device__ __forceinline__ int unpackcol(unsigned long long k) {
  return 2048 - (int)(k & 0xffffffffu);
}
__device__ __forceinline__ void merge2(unsigned long long& k1, unsigned long long& k2,
                                       unsigned long long o1, unsigned long long o2) {
  if (o1 > k1) { k2 = (k1 > o2) ? k1 : o2; k1 = o1; }
  else if (o1 > k2) { k2 = o1; }
}
// 16B-slot swizzle within one 64x128-f32 LDS row (conflict-free h-quarter reads)
__device__ __forceinline__ int sslot(int colslot, int lrow) {
  return colslot ^ (lrow & 7);
}

// ---------------- zero queue counter ----------------
__global__ __launch_bounds__(64) void zero_k(int* __restrict__ qcount) {
  if (threadIdx.x == 0) *qcount = 0;
}

// ---------------- memory_norm -> bf16 hi/lo ----------------
__global__ __launch_bounds__(64) void prep_memory_k(
    const float* __restrict__ mem, unsigned short* __restrict__ Bh,
    unsigned short* __restrict__ Bl) {
  const int m = blockIdx.x;
  const int lane = threadIdx.x;
  const float* row = mem + (size_t)m * FDIM;
  float4 a = *(const float4*)(row + lane * 4);
  float4 b = *(const float4*)(row + 256 + lane * 4);
  float s = a.x * a.x + a.y * a.y + a.z * a.z + a.w * a.w +
            b.x * b.x + b.y * b.y + b.z * b.z + b.w * b.w;
  #pragma unroll
  for (int off = 1; off < 64; off <<= 1) s += __shfl_xor(s, off);
  const float rn = 1.0f / sqrtf(fmaxf(s, 1e-12f));
  float v[8] = {a.x, a.y, a.z, a.w, b.x, b.y, b.z, b.w};
  #pragma unroll
  for (int h = 0; h < 2; ++h) {
    ushort4 hs, lo;
    #pragma unroll
    for (int q = 0; q < 4; ++q) {
      float x = v[h * 4 + q] * rn;
      unsigned short hb = f2bf(x);
      ((unsigned short*)&hs)[q] = hb;
      ((unsigned short*)&lo)[q] = f2bf(x - bf2f(hb));
    }
    const size_t e = (size_t)m * FDIM + h * 256 + lane * 4;
    *(ushort4*)(Bh + e) = hs;
    *(ushort4*)(Bl + e) = lo;
  }
}

// ---------------- transpose Bh [M][F] -> Bt [F][M] ----------------
__global__ __launch_bounds__(256) void transpose_k(
    const unsigned short* __restrict__ Bh, unsigned short* __restrict__ Bt) {
  __shared__ unsigned short t[32][33];
  const int m0 = blockIdx.x * 32, f0 = blockIdx.y * 32;
  const int tx = threadIdx.x & 31, ty = threadIdx.x >> 5;
  #pragma unroll
  for (int r = ty; r < 32; r += 8)
    t[r][tx] = Bh[(size_t)(m0 + r) * FDIM + f0 + tx];
  __syncthreads();
  #pragma unroll
  for (int r = ty; r < 32; r += 8)
    Bt[(size_t)(f0 + r) * MDIM + m0 + tx] = t[tx][r];
}

// ---------------- input row inv-norms (f32) ----------------
__global__ __launch_bounds__(256) void input_norms_k(
    const float* __restrict__ inp, float* __restrict__ inv_n) {
  const int row = blockIdx.x * 4 + (threadIdx.x >> 6);
  const int lane = threadIdx.x & 63;
  const float* x = inp + (size_t)row * FDIM;
  float4 a = *(const float4*)(x + lane * 4);
  float4 b = *(const float4*)(x + 256 + lane * 4);
  float s = a.x * a.x + a.y * a.y + a.z * a.z + a.w * a.w +
            b.x * b.x + b.y * b.y + b.z * b.z + b.w * b.w;
  #pragma unroll
  for (int off = 1; off < 64; off <<= 1) s += __shfl_xor(s, off);
  if (lane == 0) inv_n[row] = 1.0f / sqrtf(fmaxf(s, 1e-12f));
}

// ---------------- inputs_norm chunk -> bf16 (hi only) ----------------
__global__ __launch_bounds__(256) void prep_a_k(
    const float* __restrict__ inp, const float* __restrict__ inv_n,
    unsigned short* __restrict__ Ah, int baseRow) {
  const size_t q4 = (size_t)blockIdx.x * 256 + threadIdx.x;
  const size_t e = q4 * 4;
  const int lrow = (int)(e >> 9);
  const float rn = inv_n[baseRow + lrow];
  float4 x = *(const float4*)(inp + (size_t)(baseRow + lrow) * FDIM + (e & 511));
  ushort4 hs;
  hs.x = f2bf(x.x * rn); hs.y = f2bf(x.y * rn);
  hs.z = f2bf(x.z * rn); hs.w = f2bf(x.w * rn);
  *(ushort4*)(Ah + e) = hs;
}

// ------------- GEMM: C = A * B^T (B row-major [N][K]), 128x128 tile -------------
// MODE 0: plain fp32 C.  MODE 1: P=bf16(exp(10*s)) + sidecar per (row,bx)
// (esum + packed top-2) via LDS-scratch epilogue.  MODE 2: fp32 C scaled by
// rowscale[row].  SPLIT (MODE 0 only): hi/lo bf16 compensation.
template <int MODE, bool SPLIT, bool SWZ>
__global__ __launch_bounds__(256) void gemm_bt_k(
    const unsigned short* __restrict__ Ah, const unsigned short* __restrict__ Al,
    const unsigned short* __restrict__ Bh, const unsigned short* __restrict__ Bl,
    void* __restrict__ Cv, int N, int K, int nbxLog2,
    const int* __restrict__ qlimit, float* __restrict__ ssum,
    unsigned long long* __restrict__ sk1, unsigned long long* __restrict__ sk2,
    const float* __restrict__ rowscale) {
  int wg = blockIdx.x;
  if (SWZ) {  // bijective: nwg % 8 == 0 guaranteed by launcher
    const int q = gridDim.x >> 3;
    wg = (wg & 7) * q + (wg >> 3);
  }
  const int bx = wg & ((1 << nbxLog2) - 1);
  const int by = wg >> nbxLog2;
  const int m0 = by * 128, n0 = bx * 128;
  if (qlimit) {
    int lim = *qlimit; if (lim > QCAP) lim = QCAP;
    lim = (lim + 127) & ~127;
    if (m0 >= lim) return;
  }
  constexpr int SM_STAGE = (SPLIT ? 4 : 2) * 128 * 32 * 2;
  constexpr int SM_BYTES = (MODE == 1 && SM_STAGE < 65536 / 2) ? 65536 / 2 : SM_STAGE;
  __shared__ alignas(16) char smem[SM_BYTES];
  unsigned short* sAh = (unsigned short*)smem;
  unsigned short* sBh = (unsigned short*)(smem + 8192);
  unsigned short* sAl = (unsigned short*)(smem + (SPLIT ? 16384 : 0));
  unsigned short* sBl = (unsigned short*)(smem + (SPLIT ? 24576 : 8192));

  const int tid = threadIdx.x;
  const int lane = tid & 63, wave = tid >> 6;
  const int wr = wave >> 1, wc = wave & 1;
  const int lr = lane & 15, ls = lane >> 4;

  f32x4 acc[4][4] = {};

  const int row0 = wave * 32 + (lane >> 2);
  const int row1 = row0 + 16;
  const int ce = (lane & 3) * 8;
  const unsigned short* gA0 = Ah + (size_t)(m0 + row0) * K + ce;
  const unsigned short* gA1 = Ah + (size_t)(m0 + row1) * K + ce;
  const unsigned short* gB0 = Bh + (size_t)(n0 + row0) * K + ce;
  const unsigned short* gB1 = Bh + (size_t)(n0 + row1) * K + ce;
  const unsigned short* gAl0 = nullptr; const unsigned short* gAl1 = nullptr;
  const unsigned short* gBl0 = nullptr; const unsigned short* gBl1 = nullptr;
  if constexpr (SPLIT) {
    gAl0 = Al + (size_t)(m0 + row0) * K + ce;
    gAl1 = Al + (size_t)(m0 + row1) * K + ce;
    gBl0 = Bl + (size_t)(n0 + row0) * K + ce;
    gBl1 = Bl + (size_t)(n0 + row1) * K + ce;
  }
  unsigned short* lA0 = &sAh[wave * 1024];
  unsigned short* lA1 = &sAh[wave * 1024 + 512];
  unsigned short* lB0 = &sBh[wave * 1024];
  unsigned short* lB1 = &sBh[wave * 1024 + 512];
  unsigned short* lAl0 = SPLIT ? &sAl[wave * 1024] : nullptr;
  unsigned short* lAl1 = SPLIT ? &sAl[wave * 1024 + 512] : nullptr;
  unsigned short* lBl0 = SPLIT ? &sBl[wave * 1024] : nullptr;
  unsigned short* lBl1 = SPLIT ? &sBl[wave * 1024 + 512] : nullptr;

  const int nk = K >> 5;
  for (int ks = 0; ks < nk; ++ks) {
    gload16(gA0, lA0); gload16(gA1, lA1);
    gload16(gB0, lB0); gload16(gB1, lB1);
    if constexpr (SPLIT) {
      gload16(gAl0, lAl0); gload16(gAl1, lAl1);
      gload16(gBl0, lBl0); gload16(gBl1, lBl1);
    }
    gA0 += 32; gA1 += 32; gB0 += 32; gB1 += 32;
    if constexpr (SPLIT) { gAl0 += 32; gAl1 += 32; gBl0 += 32; gBl1 += 32; }
    __syncthreads();

    u16x8 fa[4], fb[4], fal[4], fbl[4];
    #pragma unroll
    for (int i = 0; i < 4; ++i) {
      const int ra = (wr * 64 + i * 16 + lr) * 32 + ls * 8;
      const int rb = (wc * 64 + i * 16 + lr) * 32 + ls * 8;
      fa[i] = *(const u16x8*)&sAh[ra];
      fb[i] = *(const u16x8*)&sBh[rb];
      if constexpr (SPLIT) {
        fal[i] = *(const u16x8*)&sAl[ra];
        fbl[i] = *(const u16x8*)&sBl[rb];
      }
    }
    #pragma unroll
    for (int i = 0; i < 4; ++i)
      #pragma unroll
      for (int j = 0; j < 4; ++j) {
        acc[i][j] = mfma16(fa[i], fb[j], acc[i][j]);
        if constexpr (SPLIT) {
          acc[i][j] = mfma16(fal[i], fb[j], acc[i][j]);
          acc[i][j] = mfma16(fa[i], fbl[j], acc[i][j]);
        }
      }
    __syncthreads();
  }

  if constexpr (MODE == 1) {
    unsigned short* P = (unsigned short*)Cv;
    float* sS = (float*)smem;          // 64 rows x 128 f32 (swizzled slots)
    #pragma unroll
    for (int ph = 0; ph < 2; ++ph) {
      __syncthreads();                 // staging / previous pass reads done
      if (wr == ph) {                  // dump this half's fragments to LDS
        #pragma unroll
        for (int i = 0; i < 4; ++i)
          #pragma unroll
          for (int q = 0; q < 4; ++q) {
            const int lrow = i * 16 + ls * 4 + q;
            float* sr = &sS[lrow * 128];
            #pragma unroll
            for (int j = 0; j < 4; ++j) {
              const int col = wc * 64 + j * 16 + lr;
              sr[sslot(col >> 2, lrow) * 4 + (col & 3)] = acc[i][j][q];
            }
          }
      }
      __syncthreads();
      // all 256 threads: (lrow, h-quarter) scans 32 f32 serially
      const int lrow = tid >> 2;
      const int h = tid & 3;
      const int grow = m0 + ph * 64 + lrow;
      const float* sr = &sS[lrow * 128];
      float esum = 0.f, m1v = -3.4e38f, m2v = -3.4e38f;
      int c1 = 2047;
      #pragma unroll
      for (int k = 0; k < 8; ++k) {
        const int lslot = k * 4 + h;   // logical 16B slot; cols ascending in k
        const f32x4 v4 = *(const f32x4*)&sr[sslot(lslot, lrow) * 4];
        unsigned short pk4[4];
        #pragma unroll
        for (int e = 0; e < 4; ++e) {
          const float s = v4[e];
          const int col = n0 + lslot * 4 + e;
          if (s > m1v) { m2v = m1v; m1v = s; c1 = col; }
          else if (s > m2v) { m2v = s; }
          const float ex = __expf(SCALE_F * s);
          esum += ex;
          pk4[e] = f2bf(ex);
        }
        *(u16x4*)&P[(size_t)grow * N + n0 + lslot * 4] = *(u16x4*)pk4;
      }
      unsigned long long k1 = packkey(m1v, c1);
      unsigned long long k2 = packkey(m2v, 2047);
      #pragma unroll
      for (int off = 1; off < 4; off <<= 1) {   // merge the 4 h-quarters
        const unsigned long long o1 = __shfl_xor(k1, off);
        const unsigned long long o2 = __shfl_xor(k2, off);
        esum += __shfl_xor(esum, off);
        merge2(k1, k2, o1, o2);
      }
      if (h == 0) {
        const size_t sp = (size_t)grow * 16 + bx;
        ssum[sp] = esum; sk1[sp] = k1; sk2[sp] = k2;
      }
    }
  } else {
    float* C = (float*)Cv;
    #pragma unroll
    for (int i = 0; i < 4; ++i) {
      const int rrow = m0 + wr * 64 + i * 16 + ls * 4;
      #pragma unroll
      for (int j = 0; j < 4; ++j) {
        const int col = n0 + wc * 64 + j * 16 + lr;
        #pragma unroll
        for (int q = 0; q < 4; ++q) {
          float v = acc[i][j][q];
          if constexpr (MODE == 2) v *= rowscale[rrow + q];
          C[(size_t)(rrow + q) * N + col] = v;
        }
      }
    }
  }
}

// ------- merge 16 sidecar partials per row: idx, rowinv, queue -------
__global__ __launch_bounds__(256) void rowstat_k(
    const float* __restrict__ ssum, const unsigned long long* __restrict__ sk1,
    const unsigned long long* __restrict__ sk2, int* __restrict__ idx,
    float* __restrict__ rowinv, int* __restrict__ queue,
    int* __restrict__ qcount, int baseRow) {
  const int row = blockIdx.x * 16 + (threadIdx.x >> 4);
  const int p = threadIdx.x & 15;
  const size_t sp = (size_t)row * 16 + p;
  float sum = ssum[sp];
  unsigned long long k1 = sk1[sp], k2 = sk2[sp];
  #pragma unroll
  for (int off = 1; off < 16; off <<= 1) {
    const unsigned long long o1 = __shfl_xor(k1, off);
    const unsigned long long o2 = __shfl_xor(k2, off);
    sum += __shfl_xor(sum, off);
    merge2(k1, k2, o1, o2);
  }
  if (p == 0) {
    const int tok = baseRow + row;
    idx[tok] = unpackcol(k1);
    rowinv[row] = 1.0f / sum;
    if (unpackval(k1) - unpackval(k2) < TAU_BF) {
      int slot = atomicAdd(qcount, 1);
      if (slot < QCAP) queue[slot] = tok;
    }
  }
}

// ------- gather queued tokens' normalized rows -> compact hi/lo matrix -------
__global__ __launch_bounds__(256) void gather_prep_k(
    const int* __restrict__ queue, const int* __restrict__ qcount,
    const float* __restrict__ inp, const float* __restrict__ inv_n,
    unsigned short* __restrict__ Qh, unsigned short* __restrict__ Ql) {
  const int w = blockIdx.x * 4 + (threadIdx.x >> 6);
  const int lane = threadIdx.x & 63;
  int cnt = *qcount; if (cnt > QCAP) cnt = QCAP;
  if (w >= cnt) return;
  const int tok = queue[w];
  const float rn = inv_n[tok];
  const float* x = inp + (size_t)tok * FDIM;
  #pragma unroll
  for (int h = 0; h < 2; ++h) {
    float4 xv = *(const float4*)(x + h * 256 + lane * 4);
    float vv[4] = {xv.x, xv.y, xv.z, xv.w};
    ushort4 hs, lo;
    #pragma unroll
    for (int q = 0; q < 4; ++q) {
      float v = vv[q] * rn;
      unsigned short hb = f2bf(v);
      ((unsigned short*)&hs)[q] = hb;
      ((unsigned short*)&lo)[q] = f2bf(v - bf2f(hb));
    }
    const size_t e = (size_t)w * FDIM + h * 256 + lane * 4;
    *(ushort4*)(Qh + e) = hs;
    *(ushort4*)(Ql + e) = lo;
  }
}

// ------- level-2: full-row top-2 on split-S; fp64 pair-decide; write idx -------
__global__ __launch_bounds__(256) void refine2_k(
    const int* __restrict__ queue, const int* __restrict__ qcount,
    const float* __restrict__ Sref, const float* __restrict__ inp,
    const float* __restrict__ mem, int* __restrict__ idx) {
  const int w = blockIdx.x * 4 + (threadIdx.x >> 6);
  const int lane = threadIdx.x & 63;
  int cnt = *qcount; if (cnt > QCAP) cnt = QCAP;
  if (w >= cnt) return;
  const int tok = queue[w];
  const float* srow = Sref + (size_t)w * MDIM;
  float m1 = -3.4e38f, m2 = -3.4e38f;
  int i1 = 0x7fffffff, i2 = 0x7fffffff;
  #pragma unroll
  for (int i = 0; i < 8; ++i) {
    const float4 vv = *(const float4*)(srow + i * 256 + lane * 4);
    const float xs[4] = {vv.x, vv.y, vv.z, vv.w};
    #pragma unroll
    for (int q = 0; q < 4; ++q) {
      const float x = xs[q];
      const int ii = i * 256 + lane * 4 + q;
      if (x > m1 || (x == m1 && ii < i1)) { m2 = m1; i2 = i1; m1 = x; i1 = ii; }
      else if (x > m2 || (x == m2 && ii < i2)) { m2 = x; i2 = ii; }
    }
  }
  #pragma unroll
  for (int off = 1; off < 64; off <<= 1) {
    const float n1 = __shfl_xor(m1, off), n2 = __shfl_xor(m2, off);
    const int j1 = __shfl_xor(i1, off), j2 = __shfl_xor(i2, off);
    if (n1 > m1 || (n1 == m1 && j1 < i1)) {
      if (m1 > n2 || (m1 == n2 && i1 < j2)) { m2 = m1; i2 = i1; }
      else { m2 = n2; i2 = j2; }
      m1 = n1; i1 = j1;
    } else if (n1 > m2 || (n1 == m2 && j1 < i2)) { m2 = n1; i2 = j1; }
  }
  int pick = i1;
  if (m1 - m2 < TAU_SP) {
    const int a = (i1 < i2) ? i1 : i2, b = (i1 < i2) ? i2 : i1;
    const float* x = inp + (size_t)tok * FDIM;
    const float* ma = mem + (size_t)a * FDIM;
    const float* mb = mem + (size_t)b * FDIM;
    double da = 0, db = 0, na = 0, nb = 0;
    #pragma unroll
    for (int j = 0; j < 8; ++j) {
      const int e = lane * 8 + j;
      const double xv = x[e], av = ma[e], bv = mb[e];
      da += xv * av; na += av * av;
      db += xv * bv; nb += bv * bv;
    }
    #pragma unroll
    for (int off = 1; off < 64; off <<= 1) {
      da += __shfl_xor(da, off); na += __shfl_xor(na, off);
      db += __shfl_xor(db, off); nb += __shfl_xor(nb, off);
    }
    const double d1 = da / sqrt(fmax(na, 1e-12));
    const double d2 = db / sqrt(fmax(nb, 1e-12));
    if (d2 > d1) pick = b;
    else pick = a;
  }
  if (lane == 0) idx[tok] = pick;
}

// ------- deterministic segment-sum: one block per code, no atomics -------
__global__ __launch_bounds__(256) void segsum_k(
    const int* __restrict__ idx, const float* __restrict__ inp,
    const float* __restrict__ inv_n, float* __restrict__ updates) {
  __shared__ int lst[256];
  __shared__ int lcnt;
  const int m = blockIdx.x;
  const int t = threadIdx.x;
  float a0 = 0.f, a1 = 0.f;
  for (int base = 0; base < N_TOK; base += 4096) {
    if (t == 0) lcnt = 0;
    __syncthreads();
    #pragma unroll
    for (int u = 0; u < 4; ++u) {
      const int off4 = (u * 256 + t) * 4;
      const int4 v = *(const int4*)&idx[base + off4];
      if (v.x == m) { int p = atomicAdd(&lcnt, 1); if (p < 256) lst[p] = base + off4 + 0; }
      if (v.y == m) { int p = atomicAdd(&lcnt, 1); if (p < 256) lst[p] = base + off4 + 1; }
      if (v.z == m) { int p = atomicAdd(&lcnt, 1); if (p < 256) lst[p] = base + off4 + 2; }
      if (v.w == m) { int p = atomicAdd(&lcnt, 1); if (p < 256) lst[p] = base + off4 + 3; }
    }
    __syncthreads();
    int c = lcnt; if (c > 256) c = 256;
    if (t == 0 && c > 1) {
      for (int i = 1; i < c; ++i) {
        int key = lst[i], j = i - 1;
        while (j >= 0 && lst[j] > key) { lst[j + 1] = lst[j]; --j; }
        lst[j + 1] = key;
      }
    }
    __syncthreads();
    for (int i = 0; i < c; ++i) {
      const int tok = lst[i];
      const float rn = inv_n[tok];
      const float2 xv = *(const float2*)&inp[(size_t)tok * FDIM + t * 2];
      a0 += xv.x * rn; a1 += xv.y * rn;
    }
    __syncthreads();
  }
  *(float2*)&updates[(size_t)m * FDIM + t * 2] = make_float2(a0, a1);
}

// ---------------- final blend (fp32 out) ----------------
__global__ __launch_bounds__(256) void final_update_k(
    const float* __restrict__ mem, const float* __restrict__ upd,
    float* __restrict__ out) {
  const size_t i = ((size_t)blockIdx.x * 256 + threadIdx.x) * 4;
  float4 m = *(const float4*)(mem + i);
  float4 u = *(const float4*)(upd + i);
  float4 r;
  r.x = m.x * 0.9f + u.x * 0.1f;
  r.y = m.y * 0.9f + u.y * 0.1f;
  r.z = m.z * 0.9f + u.z * 0.1f;
  r.w = m.w * 0.9f + u.w * 0.1f;
  *(float4*)(out + i) = r;
}

extern "C" void kernel_launch(void* const* d_in, const int* in_sizes, int n_in,
                              void* d_out, int out_size, void* d_ws, size_t ws_size,
                              hipStream_t stream) {
  const float* inputs = (const float*)d_in[0];
  const float* memory = (const float*)d_in[1];
  if (n_in >= 2 && in_sizes[0] != N_TOK * FDIM) {  // order guard
    inputs = (const float*)d_in[1];
    memory = (const float*)d_in[0];
  }
  float* out_mu = (float*)d_out;                       // [N][F] fp32
  float* out_um = out_mu + (size_t)N_TOK * FDIM;       // [M][F] fp32

  char* base = (char*)d_ws;
  size_t off = 0;
  auto take = [&](size_t bytes) -> char* {
    char* p = base + off;
    off = (off + bytes + 255) & ~(size_t)255;
    return p;
  };
  unsigned short* Bh = (unsigned short*)take((size_t)MDIM * FDIM * 2);
  unsigned short* Bl = (unsigned short*)take((size_t)MDIM * FDIM * 2);
  unsigned short* Bt = (unsigned short*)take((size_t)MDIM * FDIM * 2);
  float* inv_n = (float*)take((size_t)N_TOK * 4);
  float* updates = (float*)take((size_t)MDIM * FDIM * 4);
  int* idx = (int*)take((size_t)N_TOK * 4);
  int* queue = (int*)take((size_t)QCAP * 4);
  int* qcount = (int*)take(256);
  unsigned short* Qh = (unsigned short*)take((size_t)QCAP * FDIM * 2);
  unsigned short* Ql = (unsigned short*)take((size_t)QCAP * FDIM * 2);
  float* Sref = (float*)take((size_t)QCAP * MDIM * 4);
  const size_t fixed = off;

  // per-token: Ah 1024 + P 4096 + sidecar 16*(4+8+8)=320 + rowinv 4
  int chunkT = 32768;
  while (chunkT > 128 && fixed + (size_t)chunkT * 5700 + 8192 > ws_size)
    chunkT >>= 1;
  if (fixed + (size_t)chunkT * 5700 + 8192 > ws_size) return;  // ws too small

  unsigned short* Ah = (unsigned short*)take((size_t)chunkT * FDIM * 2);
  unsigned short* Pbuf = (unsigned short*)take((size_t)chunkT * MDIM * 2);
  float* ssum = (float*)take((size_t)chunkT * 16 * 4);
  unsigned long long* sk1 = (unsigned long long*)take((size_t)chunkT * 16 * 8);
  unsigned long long* sk2 = (unsigned long long*)take((size_t)chunkT * 16 * 8);
  float* rowinv = (float*)take((size_t)chunkT * 4);

  zero_k<<<1, 64, 0, stream>>>(qcount);
  prep_memory_k<<<MDIM, 64, 0, stream>>>(memory, Bh, Bl);
  transpose_k<<<dim3(MDIM / 32, FDIM / 32), 256, 0, stream>>>(Bh, Bt);
  input_norms_k<<<N_TOK / 4, 256, 0, stream>>>(inputs, inv_n);

  const int nby = chunkT / 128;
  for (int baseRow = 0; baseRow < N_TOK; baseRow += chunkT) {
    prep_a_k<<<chunkT / 2, 256, 0, stream>>>(inputs, inv_n, Ah, baseRow);
    // GEMM1 + exp + sidecar (S never hits HBM)
    gemm_bt_k<1, false, true><<<16 * nby, 256, 0, stream>>>(
        Ah, nullptr, Bh, nullptr, (void*)Pbuf, MDIM, FDIM, 4, nullptr,
        ssum, sk1, sk2, nullptr);
    rowstat_k<<<chunkT / 16, 256, 0, stream>>>(
        ssum, sk1, sk2, idx, rowinv, queue, qcount, baseRow);
    // GEMM2: out = (P * Bt^T) * rowinv
    gemm_bt_k<2, false, true><<<4 * nby, 256, 0, stream>>>(
        Pbuf, nullptr, Bt, nullptr, (void*)(out_mu + (size_t)baseRow * FDIM),
        FDIM, MDIM, 2, nullptr, nullptr, nullptr, nullptr, rowinv);
  }
  // two-level argmax refine: gather ambiguous rows, split-GEMM, decide idx
  gather_prep_k<<<QCAP / 4, 256, 0, stream>>>(queue, qcount, inputs, inv_n, Qh, Ql);
  gemm_bt_k<0, true, false><<<16 * (QCAP / 128), 256, 0, stream>>>(
      Qh, Ql, Bh, Bl, (void*)Sref, MDIM, FDIM, 4, qcount,
      nullptr, nullptr, nullptr, nullptr);
  refine2_k<<<QCAP / 4, 256, 0, stream>>>(queue, qcount, Sref, inputs, memory, idx);
  // deterministic segment-sum (no atomics), then blend
  segsum_k<<<MDIM, 256, 0, stream>>>(idx, inputs, inv_n, updates);
  final_update_k<<<(MDIM * FDIM / 4) / 256, 256, 0, stream>>>(memory, updates, out_um);
}

// Round 11
// 844.999 us; speedup vs baseline: 1.4199x; 1.0350x over previous
//
#include <hip/hip_runtime.h>
#include <stdint.h>

#define N_TOK   65536
#define MDIM    2048
#define FDIM    512
#define SCALE_F 10.0f
#define TAU_BF  1.2e-3f   // level-1: bf16-S ambiguity (~9 sigma)
#define TAU_SP  2e-5f     // level-2: split-S ambiguity (~100 sigma)
#define QCAP    8192

typedef __attribute__((ext_vector_type(8))) unsigned short u16x8;
typedef __attribute__((ext_vector_type(4))) unsigned short u16x4;
typedef __attribute__((ext_vector_type(8))) __bf16 bf16x8;
typedef __attribute__((ext_vector_type(4))) float f32x4;

__device__ __forceinline__ unsigned short f2bf(float f) {
  unsigned int u = __builtin_bit_cast(unsigned int, f);
  u += 0x7fffu + ((u >> 16) & 1u);   // round-to-nearest-even
  return (unsigned short)(u >> 16);
}
__device__ __forceinline__ float bf2f(unsigned short b) {
  return __builtin_bit_cast(float, (unsigned int)b << 16);
}
__device__ __forceinline__ f32x4 mfma16(u16x8 a, u16x8 b, f32x4 c) {
  return __builtin_amdgcn_mfma_f32_16x16x32_bf16(
      __builtin_bit_cast(bf16x8, a), __builtin_bit_cast(bf16x8, b), c, 0, 0, 0);
}
__device__ __forceinline__ void gload16(const unsigned short* g, unsigned short* l) {
  __builtin_amdgcn_global_load_lds(
      (const __attribute__((address_space(1))) unsigned int*)g,
      (__attribute__((address_space(3))) unsigned int*)l,
      16, 0, 0);
}
// order-preserving float->u32; tie -> smaller col wins (np.argmax)
__device__ __forceinline__ unsigned long long packkey(float x, int col) {
  unsigned u = __builtin_bit_cast(unsigned, x);
  u = (u & 0x80000000u) ? ~u : (u | 0x80000000u);
  return ((unsigned long long)u << 32) | (unsigned)(2048 - col);
}
__device__ __forceinline__ float unpackval(unsigned long long k) {
  unsigned u = (unsigned)(k >> 32);
  u = (u & 0x80000000u) ? (u & 0x7fffffffu) : ~u;
  return __builtin_bit_cast(float, u);
}
__device__ __forceinline__ int unpackcol(unsigned long long k) {
  return 2048 - (int)(k & 0xffffffffu);
}
__device__ __forceinline__ void merge2(unsigned long long& k1, unsigned long long& k2,
                                       unsigned long long o1, unsigned long long o2) {
  if (o1 > k1) { k2 = (k1 > o2) ? k1 : o2; k1 = o1; }
  else if (o1 > k2) { k2 = o1; }
}
// 16B-slot swizzle within one 32x128-f32 LDS tile row
__device__ __forceinline__ int sslot(int colslot, int lrow) {
  return colslot ^ (lrow & 7);
}

// ---------------- zero queue counter ----------------
__global__ __launch_bounds__(64) void zero_k(int* __restrict__ qcount) {
  if (threadIdx.x == 0) *qcount = 0;
}

// ---------------- memory_norm -> bf16 hi/lo ----------------
__global__ __launch_bounds__(64) void prep_memory_k(
    const float* __restrict__ mem, unsigned short* __restrict__ Bh,
    unsigned short* __restrict__ Bl) {
  const int m = blockIdx.x;
  const int lane = threadIdx.x;
  const float* row = mem + (size_t)m * FDIM;
  float4 a = *(const float4*)(row + lane * 4);
  float4 b = *(const float4*)(row + 256 + lane * 4);
  float s = a.x * a.x + a.y * a.y + a.z * a.z + a.w * a.w +
            b.x * b.x + b.y * b.y + b.z * b.z + b.w * b.w;
  #pragma unroll
  for (int off = 1; off < 64; off <<= 1) s += __shfl_xor(s, off);
  const float rn = 1.0f / sqrtf(fmaxf(s, 1e-12f));
  float v[8] = {a.x, a.y, a.z, a.w, b.x, b.y, b.z, b.w};
  #pragma unroll
  for (int h = 0; h < 2; ++h) {
    ushort4 hs, lo;
    #pragma unroll
    for (int q = 0; q < 4; ++q) {
      float x = v[h * 4 + q] * rn;
      unsigned short hb = f2bf(x);
      ((unsigned short*)&hs)[q] = hb;
      ((unsigned short*)&lo)[q] = f2bf(x - bf2f(hb));
    }
    const size_t e = (size_t)m * FDIM + h * 256 + lane * 4;
    *(ushort4*)(Bh + e) = hs;
    *(ushort4*)(Bl + e) = lo;
  }
}

// ---------------- transpose Bh [M][F] -> Bt [F][M] ----------------
__global__ __launch_bounds__(256) void transpose_k(
    const unsigned short* __restrict__ Bh, unsigned short* __restrict__ Bt) {
  __shared__ unsigned short t[32][33];
  const int m0 = blockIdx.x * 32, f0 = blockIdx.y * 32;
  const int tx = threadIdx.x & 31, ty = threadIdx.x >> 5;
  #pragma unroll
  for (int r = ty; r < 32; r += 8)
    t[r][tx] = Bh[(size_t)(m0 + r) * FDIM + f0 + tx];
  __syncthreads();
  #pragma unroll
  for (int r = ty; r < 32; r += 8)
    Bt[(size_t)(f0 + r) * MDIM + m0 + tx] = t[tx][r];
}

// ---------------- input row inv-norms (f32) ----------------
__global__ __launch_bounds__(256) void input_norms_k(
    const float* __restrict__ inp, float* __restrict__ inv_n) {
  const int row = blockIdx.x * 4 + (threadIdx.x >> 6);
  const int lane = threadIdx.x & 63;
  const float* x = inp + (size_t)row * FDIM;
  float4 a = *(const float4*)(x + lane * 4);
  float4 b = *(const float4*)(x + 256 + lane * 4);
  float s = a.x * a.x + a.y * a.y + a.z * a.z + a.w * a.w +
            b.x * b.x + b.y * b.y + b.z * b.z + b.w * b.w;
  #pragma unroll
  for (int off = 1; off < 64; off <<= 1) s += __shfl_xor(s, off);
  if (lane == 0) inv_n[row] = 1.0f / sqrtf(fmaxf(s, 1e-12f));
}

// ---------------- inputs_norm chunk -> bf16 (hi only) ----------------
__global__ __launch_bounds__(256) void prep_a_k(
    const float* __restrict__ inp, const float* __restrict__ inv_n,
    unsigned short* __restrict__ Ah, int baseRow) {
  const size_t q4 = (size_t)blockIdx.x * 256 + threadIdx.x;
  const size_t e = q4 * 4;
  const int lrow = (int)(e >> 9);
  const float rn = inv_n[baseRow + lrow];
  float4 x = *(const float4*)(inp + (size_t)(baseRow + lrow) * FDIM + (e & 511));
  ushort4 hs;
  hs.x = f2bf(x.x * rn); hs.y = f2bf(x.y * rn);
  hs.z = f2bf(x.z * rn); hs.w = f2bf(x.w * rn);
  *(ushort4*)(Ah + e) = hs;
}

// ------------- GEMM: C = A * B^T (B row-major [N][K]), 128x128 tile -------------
// MODE 0: plain fp32 C.  MODE 1: P=bf16(exp(10*s)) + sidecar per (row,bx)
// (esum + packed top-2) via 4-phase 16KB LDS-scratch epilogue.  MODE 2: fp32 C
// scaled by rowscale[row].  SPLIT (MODE 0 only): hi/lo bf16 compensation.
template <int MODE, bool SPLIT, bool SWZ>
__global__ __launch_bounds__(256) void gemm_bt_k(
    const unsigned short* __restrict__ Ah, const unsigned short* __restrict__ Al,
    const unsigned short* __restrict__ Bh, const unsigned short* __restrict__ Bl,
    void* __restrict__ Cv, int N, int K, int nbxLog2,
    const int* __restrict__ qlimit, float* __restrict__ ssum,
    unsigned long long* __restrict__ sk1, unsigned long long* __restrict__ sk2,
    const float* __restrict__ rowscale) {
  int wg = blockIdx.x;
  if (SWZ) {  // bijective: nwg % 8 == 0 guaranteed by launcher
    const int q = gridDim.x >> 3;
    wg = (wg & 7) * q + (wg >> 3);
  }
  const int bx = wg & ((1 << nbxLog2) - 1);
  const int by = wg >> nbxLog2;
  const int m0 = by * 128, n0 = bx * 128;
  if (qlimit) {
    int lim = *qlimit; if (lim > QCAP) lim = QCAP;
    lim = (lim + 127) & ~127;
    if (m0 >= lim) return;
  }
  constexpr int SM_BYTES = (SPLIT ? 4 : 2) * 128 * 32 * 2;  // 16KB non-split
  __shared__ alignas(16) char smem[SM_BYTES];
  unsigned short* sAh = (unsigned short*)smem;
  unsigned short* sBh = (unsigned short*)(smem + 8192);
  unsigned short* sAl = (unsigned short*)(smem + (SPLIT ? 16384 : 0));
  unsigned short* sBl = (unsigned short*)(smem + (SPLIT ? 24576 : 8192));

  const int tid = threadIdx.x;
  const int lane = tid & 63, wave = tid >> 6;
  const int wr = wave >> 1, wc = wave & 1;
  const int lr = lane & 15, ls = lane >> 4;

  f32x4 acc[4][4] = {};

  const int row0 = wave * 32 + (lane >> 2);
  const int row1 = row0 + 16;
  const int ce = (lane & 3) * 8;
  const unsigned short* gA0 = Ah + (size_t)(m0 + row0) * K + ce;
  const unsigned short* gA1 = Ah + (size_t)(m0 + row1) * K + ce;
  const unsigned short* gB0 = Bh + (size_t)(n0 + row0) * K + ce;
  const unsigned short* gB1 = Bh + (size_t)(n0 + row1) * K + ce;
  const unsigned short* gAl0 = nullptr; const unsigned short* gAl1 = nullptr;
  const unsigned short* gBl0 = nullptr; const unsigned short* gBl1 = nullptr;
  if constexpr (SPLIT) {
    gAl0 = Al + (size_t)(m0 + row0) * K + ce;
    gAl1 = Al + (size_t)(m0 + row1) * K + ce;
    gBl0 = Bl + (size_t)(n0 + row0) * K + ce;
    gBl1 = Bl + (size_t)(n0 + row1) * K + ce;
  }
  unsigned short* lA0 = &sAh[wave * 1024];
  unsigned short* lA1 = &sAh[wave * 1024 + 512];
  unsigned short* lB0 = &sBh[wave * 1024];
  unsigned short* lB1 = &sBh[wave * 1024 + 512];
  unsigned short* lAl0 = SPLIT ? &sAl[wave * 1024] : nullptr;
  unsigned short* lAl1 = SPLIT ? &sAl[wave * 1024 + 512] : nullptr;
  unsigned short* lBl0 = SPLIT ? &sBl[wave * 1024] : nullptr;
  unsigned short* lBl1 = SPLIT ? &sBl[wave * 1024 + 512] : nullptr;

  const int nk = K >> 5;
  for (int ks = 0; ks < nk; ++ks) {
    gload16(gA0, lA0); gload16(gA1, lA1);
    gload16(gB0, lB0); gload16(gB1, lB1);
    if constexpr (SPLIT) {
      gload16(gAl0, lAl0); gload16(gAl1, lAl1);
      gload16(gBl0, lBl0); gload16(gBl1, lBl1);
    }
    gA0 += 32; gA1 += 32; gB0 += 32; gB1 += 32;
    if constexpr (SPLIT) { gAl0 += 32; gAl1 += 32; gBl0 += 32; gBl1 += 32; }
    __syncthreads();

    u16x8 fa[4], fb[4], fal[4], fbl[4];
    #pragma unroll
    for (int i = 0; i < 4; ++i) {
      const int ra = (wr * 64 + i * 16 + lr) * 32 + ls * 8;
      const int rb = (wc * 64 + i * 16 + lr) * 32 + ls * 8;
      fa[i] = *(const u16x8*)&sAh[ra];
      fb[i] = *(const u16x8*)&sBh[rb];
      if constexpr (SPLIT) {
        fal[i] = *(const u16x8*)&sAl[ra];
        fbl[i] = *(const u16x8*)&sBl[rb];
      }
    }
    #pragma unroll
    for (int i = 0; i < 4; ++i)
      #pragma unroll
      for (int j = 0; j < 4; ++j) {
        acc[i][j] = mfma16(fa[i], fb[j], acc[i][j]);
        if constexpr (SPLIT) {
          acc[i][j] = mfma16(fal[i], fb[j], acc[i][j]);
          acc[i][j] = mfma16(fa[i], fbl[j], acc[i][j]);
        }
      }
    __syncthreads();
  }

  if constexpr (MODE == 1) {
    unsigned short* P = (unsigned short*)Cv;
    float* sS = (float*)smem;          // 32 rows x 128 f32 (swizzled 16B slots)
    #pragma unroll
    for (int ph = 0; ph < 4; ++ph) {
      __syncthreads();                 // previous phase reads (or staging) done
      if (wr == (ph >> 1)) {           // 2 waves dump rows [ph*32, ph*32+32)
        const int ibase = (ph & 1) * 2;
        #pragma unroll
        for (int di = 0; di < 2; ++di)
          #pragma unroll
          for (int q = 0; q < 4; ++q) {
            const int lrow = di * 16 + ls * 4 + q;   // 0..31 within phase
            float* sr = &sS[lrow * 128];
            #pragma unroll
            for (int j = 0; j < 4; ++j) {
              const int col = wc * 64 + j * 16 + lr;
              sr[sslot(col >> 2, lrow) * 4 + (col & 3)] = acc[ibase + di][j][q];
            }
          }
      }
      __syncthreads();
      // 256 threads: 8 threads/row, each scans 16 f32 serially
      const int lrow = tid >> 3;
      const int h = tid & 7;
      const int grow = m0 + ph * 32 + lrow;
      const float* sr = &sS[lrow * 128];
      float esum = 0.f, m1v = -3.4e38f, m2v = -3.4e38f;
      int c1 = 2047;
      #pragma unroll
      for (int k = 0; k < 4; ++k) {
        const int lslot = k * 8 + h;   // logical 16B slot; cols ascending in k
        const f32x4 v4 = *(const f32x4*)&sr[sslot(lslot, lrow) * 4];
        unsigned short pk4[4];
        #pragma unroll
        for (int e = 0; e < 4; ++e) {
          const float s = v4[e];
          const int col = n0 + lslot * 4 + e;
          if (s > m1v) { m2v = m1v; m1v = s; c1 = col; }
          else if (s > m2v) { m2v = s; }
          const float ex = __expf(SCALE_F * s);
          esum += ex;
          pk4[e] = f2bf(ex);
        }
        *(u16x4*)&P[(size_t)grow * N + n0 + lslot * 4] = *(u16x4*)pk4;
      }
      unsigned long long k1 = packkey(m1v, c1);
      unsigned long long k2 = packkey(m2v, 2047);
      #pragma unroll
      for (int off = 1; off < 8; off <<= 1) {   // merge the 8 col-groups
        const unsigned long long o1 = __shfl_xor(k1, off);
        const unsigned long long o2 = __shfl_xor(k2, off);
        esum += __shfl_xor(esum, off);
        merge2(k1, k2, o1, o2);
      }
      if (h == 0) {
        const size_t sp = (size_t)grow * 16 + bx;
        ssum[sp] = esum; sk1[sp] = k1; sk2[sp] = k2;
      }
    }
  } else {
    float* C = (float*)Cv;
    #pragma unroll
    for (int i = 0; i < 4; ++i) {
      const int rrow = m0 + wr * 64 + i * 16 + ls * 4;
      #pragma unroll
      for (int j = 0; j < 4; ++j) {
        const int col = n0 + wc * 64 + j * 16 + lr;
        #pragma unroll
        for (int q = 0; q < 4; ++q) {
          float v = acc[i][j][q];
          if constexpr (MODE == 2) v *= rowscale[rrow + q];
          C[(size_t)(rrow + q) * N + col] = v;
        }
      }
    }
  }
}

// ------- merge 16 sidecar partials per row: idx, rowinv, queue -------
__global__ __launch_bounds__(256) void rowstat_k(
    const float* __restrict__ ssum, const unsigned long long* __restrict__ sk1,
    const unsigned long long* __restrict__ sk2, int* __restrict__ idx,
    float* __restrict__ rowinv, int* __restrict__ queue,
    int* __restrict__ qcount, int baseRow) {
  const int row = blockIdx.x * 16 + (threadIdx.x >> 4);
  const int p = threadIdx.x & 15;
  const size_t sp = (size_t)row * 16 + p;
  float sum = ssum[sp];
  unsigned long long k1 = sk1[sp], k2 = sk2[sp];
  #pragma unroll
  for (int off = 1; off < 16; off <<= 1) {
    const unsigned long long o1 = __shfl_xor(k1, off);
    const unsigned long long o2 = __shfl_xor(k2, off);
    sum += __shfl_xor(sum, off);
    merge2(k1, k2, o1, o2);
  }
  if (p == 0) {
    const int tok = baseRow + row;
    idx[tok] = unpackcol(k1);
    rowinv[row] = 1.0f / sum;
    if (unpackval(k1) - unpackval(k2) < TAU_BF) {
      int slot = atomicAdd(qcount, 1);
      if (slot < QCAP) queue[slot] = tok;
    }
  }
}

// ------- gather queued tokens' normalized rows -> compact hi/lo matrix -------
__global__ __launch_bounds__(256) void gather_prep_k(
    const int* __restrict__ queue, const int* __restrict__ qcount,
    const float* __restrict__ inp, const float* __restrict__ inv_n,
    unsigned short* __restrict__ Qh, unsigned short* __restrict__ Ql) {
  const int w = blockIdx.x * 4 + (threadIdx.x >> 6);
  const int lane = threadIdx.x & 63;
  int cnt = *qcount; if (cnt > QCAP) cnt = QCAP;
  if (w >= cnt) return;
  const int tok = queue[w];
  const float rn = inv_n[tok];
  const float* x = inp + (size_t)tok * FDIM;
  #pragma unroll
  for (int h = 0; h < 2; ++h) {
    float4 xv = *(const float4*)(x + h * 256 + lane * 4);
    float vv[4] = {xv.x, xv.y, xv.z, xv.w};
    ushort4 hs, lo;
    #pragma unroll
    for (int q = 0; q < 4; ++q) {
      float v = vv[q] * rn;
      unsigned short hb = f2bf(v);
      ((unsigned short*)&hs)[q] = hb;
      ((unsigned short*)&lo)[q] = f2bf(v - bf2f(hb));
    }
    const size_t e = (size_t)w * FDIM + h * 256 + lane * 4;
    *(ushort4*)(Qh + e) = hs;
    *(ushort4*)(Ql + e) = lo;
  }
}

// ------- level-2: full-row top-2 on split-S; fp64 pair-decide; write idx -------
__global__ __launch_bounds__(256) void refine2_k(
    const int* __restrict__ queue, const int* __restrict__ qcount,
    const float* __restrict__ Sref, const float* __restrict__ inp,
    const float* __restrict__ mem, int* __restrict__ idx) {
  const int w = blockIdx.x * 4 + (threadIdx.x >> 6);
  const int lane = threadIdx.x & 63;
  int cnt = *qcount; if (cnt > QCAP) cnt = QCAP;
  if (w >= cnt) return;
  const int tok = queue[w];
  const float* srow = Sref + (size_t)w * MDIM;
  float m1 = -3.4e38f, m2 = -3.4e38f;
  int i1 = 0x7fffffff, i2 = 0x7fffffff;
  #pragma unroll
  for (int i = 0; i < 8; ++i) {
    const float4 vv = *(const float4*)(srow + i * 256 + lane * 4);
    const float xs[4] = {vv.x, vv.y, vv.z, vv.w};
    #pragma unroll
    for (int q = 0; q < 4; ++q) {
      const float x = xs[q];
      const int ii = i * 256 + lane * 4 + q;
      if (x > m1 || (x == m1 && ii < i1)) { m2 = m1; i2 = i1; m1 = x; i1 = ii; }
      else if (x > m2 || (x == m2 && ii < i2)) { m2 = x; i2 = ii; }
    }
  }
  #pragma unroll
  for (int off = 1; off < 64; off <<= 1) {
    const float n1 = __shfl_xor(m1, off), n2 = __shfl_xor(m2, off);
    const int j1 = __shfl_xor(i1, off), j2 = __shfl_xor(i2, off);
    if (n1 > m1 || (n1 == m1 && j1 < i1)) {
      if (m1 > n2 || (m1 == n2 && i1 < j2)) { m2 = m1; i2 = i1; }
      else { m2 = n2; i2 = j2; }
      m1 = n1; i1 = j1;
    } else if (n1 > m2 || (n1 == m2 && j1 < i2)) { m2 = n1; i2 = j1; }
  }
  int pick = i1;
  if (m1 - m2 < TAU_SP) {
    const int a = (i1 < i2) ? i1 : i2, b = (i1 < i2) ? i2 : i1;
    const float* x = inp + (size_t)tok * FDIM;
    const float* ma = mem + (size_t)a * FDIM;
    const float* mb = mem + (size_t)b * FDIM;
    double da = 0, db = 0, na = 0, nb = 0;
    #pragma unroll
    for (int j = 0; j < 8; ++j) {
      const int e = lane * 8 + j;
      const double xv = x[e], av = ma[e], bv = mb[e];
      da += xv * av; na += av * av;
      db += xv * bv; nb += bv * bv;
    }
    #pragma unroll
    for (int off = 1; off < 64; off <<= 1) {
      da += __shfl_xor(da, off); na += __shfl_xor(na, off);
      db += __shfl_xor(db, off); nb += __shfl_xor(nb, off);
    }
    const double d1 = da / sqrt(fmax(na, 1e-12));
    const double d2 = db / sqrt(fmax(nb, 1e-12));
    if (d2 > d1) pick = b;
    else pick = a;
  }
  if (lane == 0) idx[tok] = pick;
}

// ------- deterministic segment-sum: one block per code, no atomics -------
__global__ __launch_bounds__(256) void segsum_k(
    const int* __restrict__ idx, const float* __restrict__ inp,
    const float* __restrict__ inv_n, float* __restrict__ updates) {
  __shared__ int lst[256];
  __shared__ int lcnt;
  const int m = blockIdx.x;
  const int t = threadIdx.x;
  float a0 = 0.f, a1 = 0.f;
  for (int base = 0; base < N_TOK; base += 4096) {
    if (t == 0) lcnt = 0;
    __syncthreads();
    #pragma unroll
    for (int u = 0; u < 4; ++u) {
      const int off4 = (u * 256 + t) * 4;
      const int4 v = *(const int4*)&idx[base + off4];
      if (v.x == m) { int p = atomicAdd(&lcnt, 1); if (p < 256) lst[p] = base + off4 + 0; }
      if (v.y == m) { int p = atomicAdd(&lcnt, 1); if (p < 256) lst[p] = base + off4 + 1; }
      if (v.z == m) { int p = atomicAdd(&lcnt, 1); if (p < 256) lst[p] = base + off4 + 2; }
      if (v.w == m) { int p = atomicAdd(&lcnt, 1); if (p < 256) lst[p] = base + off4 + 3; }
    }
    __syncthreads();
    int c = lcnt; if (c > 256) c = 256;
    if (t == 0 && c > 1) {
      for (int i = 1; i < c; ++i) {
        int key = lst[i], j = i - 1;
        while (j >= 0 && lst[j] > key) { lst[j + 1] = lst[j]; --j; }
        lst[j + 1] = key;
      }
    }
    __syncthreads();
    for (int i = 0; i < c; ++i) {
      const int tok = lst[i];
      const float rn = inv_n[tok];
      const float2 xv = *(const float2*)&inp[(size_t)tok * FDIM + t * 2];
      a0 += xv.x * rn; a1 += xv.y * rn;
    }
    __syncthreads();
  }
  *(float2*)&updates[(size_t)m * FDIM + t * 2] = make_float2(a0, a1);
}

// ---------------- final blend (fp32 out) ----------------
__global__ __launch_bounds__(256) void final_update_k(
    const float* __restrict__ mem, const float* __restrict__ upd,
    float* __restrict__ out) {
  const size_t i = ((size_t)blockIdx.x * 256 + threadIdx.x) * 4;
  float4 m = *(const float4*)(mem + i);
  float4 u = *(const float4*)(upd + i);
  float4 r;
  r.x = m.x * 0.9f + u.x * 0.1f;
  r.y = m.y * 0.9f + u.y * 0.1f;
  r.z = m.z * 0.9f + u.z * 0.1f;
  r.w = m.w * 0.9f + u.w * 0.1f;
  *(float4*)(out + i) = r;
}

extern "C" void kernel_launch(void* const* d_in, const int* in_sizes, int n_in,
                              void* d_out, int out_size, void* d_ws, size_t ws_size,
                              hipStream_t stream) {
  const float* inputs = (const float*)d_in[0];
  const float* memory = (const float*)d_in[1];
  if (n_in >= 2 && in_sizes[0] != N_TOK * FDIM) {  // order guard
    inputs = (const float*)d_in[1];
    memory = (const float*)d_in[0];
  }
  float* out_mu = (float*)d_out;                       // [N][F] fp32
  float* out_um = out_mu + (size_t)N_TOK * FDIM;       // [M][F] fp32

  char* base = (char*)d_ws;
  size_t off = 0;
  auto take = [&](size_t bytes) -> char* {
    char* p = base + off;
    off = (off + bytes + 255) & ~(size_t)255;
    return p;
  };
  unsigned short* Bh = (unsigned short*)take((size_t)MDIM * FDIM * 2);
  unsigned short* Bl = (unsigned short*)take((size_t)MDIM * FDIM * 2);
  unsigned short* Bt = (unsigned short*)take((size_t)MDIM * FDIM * 2);
  float* inv_n = (float*)take((size_t)N_TOK * 4);
  float* updates = (float*)take((size_t)MDIM * FDIM * 4);
  int* idx = (int*)take((size_t)N_TOK * 4);
  int* queue = (int*)take((size_t)QCAP * 4);
  int* qcount = (int*)take(256);
  unsigned short* Qh = (unsigned short*)take((size_t)QCAP * FDIM * 2);
  unsigned short* Ql = (unsigned short*)take((size_t)QCAP * FDIM * 2);
  float* Sref = (float*)take((size_t)QCAP * MDIM * 4);
  const size_t fixed = off;

  // per-token: Ah 1024 + P 4096 + sidecar 16*(4+8+8)=320 + rowinv 4
  int chunkT = 65536;  // single pass if ws allows
  while (chunkT > 128 && fixed + (size_t)chunkT * 5700 + 8192 > ws_size)
    chunkT >>= 1;
  if (fixed + (size_t)chunkT * 5700 + 8192 > ws_size) return;  // ws too small

  unsigned short* Ah = (unsigned short*)take((size_t)chunkT * FDIM * 2);
  unsigned short* Pbuf = (unsigned short*)take((size_t)chunkT * MDIM * 2);
  float* ssum = (float*)take((size_t)chunkT * 16 * 4);
  unsigned long long* sk1 = (unsigned long long*)take((size_t)chunkT * 16 * 8);
  unsigned long long* sk2 = (unsigned long long*)take((size_t)chunkT * 16 * 8);
  float* rowinv = (float*)take((size_t)chunkT * 4);

  zero_k<<<1, 64, 0, stream>>>(qcount);
  prep_memory_k<<<MDIM, 64, 0, stream>>>(memory, Bh, Bl);
  transpose_k<<<dim3(MDIM / 32, FDIM / 32), 256, 0, stream>>>(Bh, Bt);
  input_norms_k<<<N_TOK / 4, 256, 0, stream>>>(inputs, inv_n);

  const int nby = chunkT / 128;
  for (int baseRow = 0; baseRow < N_TOK; baseRow += chunkT) {
    prep_a_k<<<chunkT / 2, 256, 0, stream>>>(inputs, inv_n, Ah, baseRow);
    // GEMM1 + exp + sidecar (S never hits HBM)
    gemm_bt_k<1, false, true><<<16 * nby, 256, 0, stream>>>(
        Ah, nullptr, Bh, nullptr, (void*)Pbuf, MDIM, FDIM, 4, nullptr,
        ssum, sk1, sk2, nullptr);
    rowstat_k<<<chunkT / 16, 256, 0, stream>>>(
        ssum, sk1, sk2, idx, rowinv, queue, qcount, baseRow);
    // GEMM2: out = (P * Bt^T) * rowinv
    gemm_bt_k<2, false, true><<<4 * nby, 256, 0, stream>>>(
        Pbuf, nullptr, Bt, nullptr, (void*)(out_mu + (size_t)baseRow * FDIM),
        FDIM, MDIM, 2, nullptr, nullptr, nullptr, nullptr, rowinv);
  }
  // two-level argmax refine: gather ambiguous rows, split-GEMM, decide idx
  gather_prep_k<<<QCAP / 4, 256, 0, stream>>>(queue, qcount, inputs, inv_n, Qh, Ql);
  gemm_bt_k<0, true, false><<<16 * (QCAP / 128), 256, 0, stream>>>(
      Qh, Ql, Bh, Bl, (void*)Sref, MDIM, FDIM, 4, qcount,
      nullptr, nullptr, nullptr, nullptr);
  refine2_k<<<QCAP / 4, 256, 0, stream>>>(queue, qcount, Sref, inputs, memory, idx);
  // deterministic segment-sum (no atomics), then blend
  segsum_k<<<MDIM, 256, 0, stream>>>(idx, inputs, inv_n, updates);
  final_update_k<<<(MDIM * FDIM / 4) / 256, 256, 0, stream>>>(memory, updates, out_um);
}

// Round 12
// 751.142 us; speedup vs baseline: 1.5973x; 1.1250x over previous
//
#include <hip/hip_runtime.h>
#include <stdint.h>

#define N_TOK   65536
#define MDIM    2048
#define FDIM    512
#define SCALE_F 10.0f
#define TAU_BF  1.2e-3f   // level-1: bf16-S ambiguity (~9 sigma)
#define TAU_SP  2e-5f     // level-2: split-S ambiguity (~100 sigma)
#define QCAP    8192

typedef __attribute__((ext_vector_type(8))) unsigned short u16x8;
typedef __attribute__((ext_vector_type(4))) unsigned short u16x4;
typedef __attribute__((ext_vector_type(8))) __bf16 bf16x8;
typedef __attribute__((ext_vector_type(4))) float f32x4;

__device__ __forceinline__ unsigned short f2bf(float f) {
  unsigned int u = __builtin_bit_cast(unsigned int, f);
  u += 0x7fffu + ((u >> 16) & 1u);   // round-to-nearest-even
  return (unsigned short)(u >> 16);
}
__device__ __forceinline__ float bf2f(unsigned short b) {
  return __builtin_bit_cast(float, (unsigned int)b << 16);
}
__device__ __forceinline__ f32x4 mfma16(u16x8 a, u16x8 b, f32x4 c) {
  return __builtin_amdgcn_mfma_f32_16x16x32_bf16(
      __builtin_bit_cast(bf16x8, a), __builtin_bit_cast(bf16x8, b), c, 0, 0, 0);
}
__device__ __forceinline__ void gload16(const unsigned short* g, unsigned short* l) {
  __builtin_amdgcn_global_load_lds(
      (const __attribute__((address_space(1))) unsigned int*)g,
      (__attribute__((address_space(3))) unsigned int*)l,
      16, 0, 0);
}
// order-preserving float->u32; tie -> smaller col wins (np.argmax)
__device__ __forceinline__ unsigned long long packkey(float x, int col) {
  unsigned u = __builtin_bit_cast(unsigned, x);
  u = (u & 0x80000000u) ? ~u : (u | 0x80000000u);
  return ((unsigned long long)u << 32) | (unsigned)(2048 - col);
}
__device__ __forceinline__ float unpackval(unsigned long long k) {
  unsigned u = (unsigned)(k >> 32);
  u = (u & 0x80000000u) ? (u & 0x7fffffffu) : ~u;
  return __builtin_bit_cast(float, u);
}
__device__ __forceinline__ int unpackcol(unsigned long long k) {
  return 2048 - (int)(k & 0xffffffffu);
}
__device__ __forceinline__ void merge2(unsigned long long& k1, unsigned long long& k2,
                                       unsigned long long o1, unsigned long long o2) {
  if (o1 > k1) { k2 = (k1 > o2) ? k1 : o2; k1 = o1; }
  else if (o1 > k2) { k2 = o1; }
}
// 16B-slot swizzle within one 32x128-f32 LDS tile row
__device__ __forceinline__ int sslot(int colslot, int lrow) {
  return colslot ^ (lrow & 7);
}

// ---------------- zero queue counter ----------------
__global__ __launch_bounds__(64) void zero_k(int* __restrict__ qcount) {
  if (threadIdx.x == 0) *qcount = 0;
}

// ---------------- memory_norm -> bf16 hi/lo ----------------
__global__ __launch_bounds__(64) void prep_memory_k(
    const float* __restrict__ mem, unsigned short* __restrict__ Bh,
    unsigned short* __restrict__ Bl) {
  const int m = blockIdx.x;
  const int lane = threadIdx.x;
  const float* row = mem + (size_t)m * FDIM;
  float4 a = *(const float4*)(row + lane * 4);
  float4 b = *(const float4*)(row + 256 + lane * 4);
  float s = a.x * a.x + a.y * a.y + a.z * a.z + a.w * a.w +
            b.x * b.x + b.y * b.y + b.z * b.z + b.w * b.w;
  #pragma unroll
  for (int off = 1; off < 64; off <<= 1) s += __shfl_xor(s, off);
  const float rn = 1.0f / sqrtf(fmaxf(s, 1e-12f));
  float v[8] = {a.x, a.y, a.z, a.w, b.x, b.y, b.z, b.w};
  #pragma unroll
  for (int h = 0; h < 2; ++h) {
    ushort4 hs, lo;
    #pragma unroll
    for (int q = 0; q < 4; ++q) {
      float x = v[h * 4 + q] * rn;
      unsigned short hb = f2bf(x);
      ((unsigned short*)&hs)[q] = hb;
      ((unsigned short*)&lo)[q] = f2bf(x - bf2f(hb));
    }
    const size_t e = (size_t)m * FDIM + h * 256 + lane * 4;
    *(ushort4*)(Bh + e) = hs;
    *(ushort4*)(Bl + e) = lo;
  }
}

// ---------------- transpose Bh [M][F] -> Bt [F][M] ----------------
__global__ __launch_bounds__(256) void transpose_k(
    const unsigned short* __restrict__ Bh, unsigned short* __restrict__ Bt) {
  __shared__ unsigned short t[32][33];
  const int m0 = blockIdx.x * 32, f0 = blockIdx.y * 32;
  const int tx = threadIdx.x & 31, ty = threadIdx.x >> 5;
  #pragma unroll
  for (int r = ty; r < 32; r += 8)
    t[r][tx] = Bh[(size_t)(m0 + r) * FDIM + f0 + tx];
  __syncthreads();
  #pragma unroll
  for (int r = ty; r < 32; r += 8)
    Bt[(size_t)(f0 + r) * MDIM + m0 + tx] = t[tx][r];
}

// ------- fused: input row inv-norm + inputs_norm -> bf16 (one pass) -------
__global__ __launch_bounds__(256) void prep_a_k(
    const float* __restrict__ inp, float* __restrict__ inv_n,
    unsigned short* __restrict__ Ah, int baseRow) {
  const int r = blockIdx.x * 4 + (threadIdx.x >> 6);   // chunk-local row
  const int lane = threadIdx.x & 63;
  const int grow = baseRow + r;
  const float* x = inp + (size_t)grow * FDIM;
  float4 a = *(const float4*)(x + lane * 4);
  float4 b = *(const float4*)(x + 256 + lane * 4);
  float s = a.x * a.x + a.y * a.y + a.z * a.z + a.w * a.w +
            b.x * b.x + b.y * b.y + b.z * b.z + b.w * b.w;
  #pragma unroll
  for (int off = 1; off < 64; off <<= 1) s += __shfl_xor(s, off);
  const float rn = 1.0f / sqrtf(fmaxf(s, 1e-12f));
  if (lane == 0) inv_n[grow] = rn;
  ushort4 h0, h1;
  h0.x = f2bf(a.x * rn); h0.y = f2bf(a.y * rn);
  h0.z = f2bf(a.z * rn); h0.w = f2bf(a.w * rn);
  h1.x = f2bf(b.x * rn); h1.y = f2bf(b.y * rn);
  h1.z = f2bf(b.z * rn); h1.w = f2bf(b.w * rn);
  *(ushort4*)(Ah + (size_t)r * FDIM + lane * 4) = h0;
  *(ushort4*)(Ah + (size_t)r * FDIM + 256 + lane * 4) = h1;
}

// ------------- GEMM: C = A * B^T (B row-major [N][K]), 128x128 tile -------------
// Double-buffered LDS (T3-minimum): stage tile k+1 before computing tile k,
// single barrier per K-step (its implicit vmcnt(0) lands after MFMA).
// MODE 0: plain fp32 C.  MODE 1: P=bf16(exp(10*s)) + sidecar per (row,bx)
// via 4-phase 16KB LDS-scratch epilogue (aliases buf0).  MODE 2: fp32 C
// scaled by rowscale[row].  SPLIT (MODE 0 only): hi/lo bf16 compensation.
template <int MODE, bool SPLIT, bool SWZ>
__global__ __launch_bounds__(256) void gemm_bt_k(
    const unsigned short* __restrict__ Ah, const unsigned short* __restrict__ Al,
    const unsigned short* __restrict__ Bh, const unsigned short* __restrict__ Bl,
    void* __restrict__ Cv, int N, int K, int nbxLog2,
    const int* __restrict__ qlimit, float* __restrict__ ssum,
    unsigned long long* __restrict__ sk1, unsigned long long* __restrict__ sk2,
    const float* __restrict__ rowscale) {
  int wg = blockIdx.x;
  if (SWZ) {  // bijective: nwg % 8 == 0 guaranteed by launcher
    const int q = gridDim.x >> 3;
    wg = (wg & 7) * q + (wg >> 3);
  }
  const int bx = wg & ((1 << nbxLog2) - 1);
  const int by = wg >> nbxLog2;
  const int m0 = by * 128, n0 = bx * 128;
  if (qlimit) {
    int lim = *qlimit; if (lim > QCAP) lim = QCAP;
    lim = (lim + 127) & ~127;
    if (m0 >= lim) return;
  }
  constexpr int BUF_B = (SPLIT ? 4 : 2) * 8192;       // bytes per staging buffer
  __shared__ alignas(16) char smem[2 * BUF_B];

  const int tid = threadIdx.x;
  const int lane = tid & 63, wave = tid >> 6;
  const int wr = wave >> 1, wc = wave & 1;
  const int lr = lane & 15, ls = lane >> 4;

  f32x4 acc[4][4] = {};

  const int row0 = wave * 32 + (lane >> 2);
  const int row1 = row0 + 16;
  const int ce = (lane & 3) * 8;
  const unsigned short* gA0 = Ah + (size_t)(m0 + row0) * K + ce;
  const unsigned short* gA1 = Ah + (size_t)(m0 + row1) * K + ce;
  const unsigned short* gB0 = Bh + (size_t)(n0 + row0) * K + ce;
  const unsigned short* gB1 = Bh + (size_t)(n0 + row1) * K + ce;
  const unsigned short* gAl0 = nullptr; const unsigned short* gAl1 = nullptr;
  const unsigned short* gBl0 = nullptr; const unsigned short* gBl1 = nullptr;
  if constexpr (SPLIT) {
    gAl0 = Al + (size_t)(m0 + row0) * K + ce;
    gAl1 = Al + (size_t)(m0 + row1) * K + ce;
    gBl0 = Bl + (size_t)(n0 + row0) * K + ce;
    gBl1 = Bl + (size_t)(n0 + row1) * K + ce;
  }

  auto stage = [&](int buf) {
    char* sb = smem + buf * BUF_B;
    unsigned short* bAh = (unsigned short*)sb;
    unsigned short* bBh = (unsigned short*)(sb + 8192);
    gload16(gA0, &bAh[wave * 1024]); gload16(gA1, &bAh[wave * 1024 + 512]);
    gload16(gB0, &bBh[wave * 1024]); gload16(gB1, &bBh[wave * 1024 + 512]);
    if constexpr (SPLIT) {
      unsigned short* bAl = (unsigned short*)(sb + 16384);
      unsigned short* bBl = (unsigned short*)(sb + 24576);
      gload16(gAl0, &bAl[wave * 1024]); gload16(gAl1, &bAl[wave * 1024 + 512]);
      gload16(gBl0, &bBl[wave * 1024]); gload16(gBl1, &bBl[wave * 1024 + 512]);
    }
    gA0 += 32; gA1 += 32; gB0 += 32; gB1 += 32;
    if constexpr (SPLIT) { gAl0 += 32; gAl1 += 32; gBl0 += 32; gBl1 += 32; }
  };

  const int nk = K >> 5;
  stage(0);
  __syncthreads();   // drains vmcnt -> buf0 visible
  for (int ks = 0; ks < nk; ++ks) {
    const int cur = ks & 1;
    if (ks + 1 < nk) stage(cur ^ 1);   // loads fly during MFMA below
    const char* sb = smem + cur * BUF_B;
    const unsigned short* cAh = (const unsigned short*)sb;
    const unsigned short* cBh = (const unsigned short*)(sb + 8192);
    u16x8 fa[4], fb[4], fal[4], fbl[4];
    #pragma unroll
    for (int i = 0; i < 4; ++i) {
      const int ra = (wr * 64 + i * 16 + lr) * 32 + ls * 8;
      const int rb = (wc * 64 + i * 16 + lr) * 32 + ls * 8;
      fa[i] = *(const u16x8*)&cAh[ra];
      fb[i] = *(const u16x8*)&cBh[rb];
      if constexpr (SPLIT) {
        fal[i] = *(const u16x8*)&((const unsigned short*)(sb + 16384))[ra];
        fbl[i] = *(const u16x8*)&((const unsigned short*)(sb + 24576))[rb];
      }
    }
    #pragma unroll
    for (int i = 0; i < 4; ++i)
      #pragma unroll
      for (int j = 0; j < 4; ++j) {
        acc[i][j] = mfma16(fa[i], fb[j], acc[i][j]);
        if constexpr (SPLIT) {
          acc[i][j] = mfma16(fal[i], fb[j], acc[i][j]);
          acc[i][j] = mfma16(fa[i], fbl[j], acc[i][j]);
        }
      }
    __syncthreads();   // implicit vmcnt(0): next buf staged; reads of cur done
  }

  if constexpr (MODE == 1) {
    unsigned short* P = (unsigned short*)Cv;
    float* sS = (float*)smem;          // 32 rows x 128 f32 (swizzled 16B slots)
    #pragma unroll
    for (int ph = 0; ph < 4; ++ph) {
      __syncthreads();                 // previous phase reads done
      if (wr == (ph >> 1)) {           // 2 waves dump rows [ph*32, ph*32+32)
        const int ibase = (ph & 1) * 2;
        #pragma unroll
        for (int di = 0; di < 2; ++di)
          #pragma unroll
          for (int q = 0; q < 4; ++q) {
            const int lrow = di * 16 + ls * 4 + q;   // 0..31 within phase
            float* sr = &sS[lrow * 128];
            #pragma unroll
            for (int j = 0; j < 4; ++j) {
              const int col = wc * 64 + j * 16 + lr;
              sr[sslot(col >> 2, lrow) * 4 + (col & 3)] = acc[ibase + di][j][q];
            }
          }
      }
      __syncthreads();
      // 256 threads: 8 threads/row, each scans 16 f32 serially
      const int lrow = tid >> 3;
      const int h = tid & 7;
      const int grow = m0 + ph * 32 + lrow;
      const float* sr = &sS[lrow * 128];
      float esum = 0.f, m1v = -3.4e38f, m2v = -3.4e38f;
      int c1 = 2047;
      #pragma unroll
      for (int k = 0; k < 4; ++k) {
        const int lslot = k * 8 + h;   // logical 16B slot; cols ascending in k
        const f32x4 v4 = *(const f32x4*)&sr[sslot(lslot, lrow) * 4];
        unsigned short pk4[4];
        #pragma unroll
        for (int e = 0; e < 4; ++e) {
          const float s = v4[e];
          const int col = n0 + lslot * 4 + e;
          if (s > m1v) { m2v = m1v; m1v = s; c1 = col; }
          else if (s > m2v) { m2v = s; }
          const float ex = __expf(SCALE_F * s);
          esum += ex;
          pk4[e] = f2bf(ex);
        }
        *(u16x4*)&P[(size_t)grow * N + n0 + lslot * 4] = *(u16x4*)pk4;
      }
      unsigned long long k1 = packkey(m1v, c1);
      unsigned long long k2 = packkey(m2v, 2047);
      #pragma unroll
      for (int off = 1; off < 8; off <<= 1) {   // merge the 8 col-groups
        const unsigned long long o1 = __shfl_xor(k1, off);
        const unsigned long long o2 = __shfl_xor(k2, off);
        esum += __shfl_xor(esum, off);
        merge2(k1, k2, o1, o2);
      }
      if (h == 0) {
        const size_t sp = (size_t)grow * 16 + bx;
        ssum[sp] = esum; sk1[sp] = k1; sk2[sp] = k2;
      }
    }
  } else {
    float* C = (float*)Cv;
    #pragma unroll
    for (int i = 0; i < 4; ++i) {
      const int rrow = m0 + wr * 64 + i * 16 + ls * 4;
      #pragma unroll
      for (int j = 0; j < 4; ++j) {
        const int col = n0 + wc * 64 + j * 16 + lr;
        #pragma unroll
        for (int q = 0; q < 4; ++q) {
          float v = acc[i][j][q];
          if constexpr (MODE == 2) v *= rowscale[rrow + q];
          C[(size_t)(rrow + q) * N + col] = v;
        }
      }
    }
  }
}

// ------- merge 16 sidecar partials per row: idx, rowinv, queue -------
__global__ __launch_bounds__(256) void rowstat_k(
    const float* __restrict__ ssum, const unsigned long long* __restrict__ sk1,
    const unsigned long long* __restrict__ sk2, int* __restrict__ idx,
    float* __restrict__ rowinv, int* __restrict__ queue,
    int* __restrict__ qcount, int baseRow) {
  const int row = blockIdx.x * 16 + (threadIdx.x >> 4);
  const int p = threadIdx.x & 15;
  const size_t sp = (size_t)row * 16 + p;
  float sum = ssum[sp];
  unsigned long long k1 = sk1[sp], k2 = sk2[sp];
  #pragma unroll
  for (int off = 1; off < 16; off <<= 1) {
    const unsigned long long o1 = __shfl_xor(k1, off);
    const unsigned long long o2 = __shfl_xor(k2, off);
    sum += __shfl_xor(sum, off);
    merge2(k1, k2, o1, o2);
  }
  if (p == 0) {
    const int tok = baseRow + row;
    idx[tok] = unpackcol(k1);
    rowinv[row] = 1.0f / sum;
    if (unpackval(k1) - unpackval(k2) < TAU_BF) {
      int slot = atomicAdd(qcount, 1);
      if (slot < QCAP) queue[slot] = tok;
    }
  }
}

// ------- gather queued tokens' normalized rows -> compact hi/lo matrix -------
__global__ __launch_bounds__(256) void gather_prep_k(
    const int* __restrict__ queue, const int* __restrict__ qcount,
    const float* __restrict__ inp, const float* __restrict__ inv_n,
    unsigned short* __restrict__ Qh, unsigned short* __restrict__ Ql) {
  const int w = blockIdx.x * 4 + (threadIdx.x >> 6);
  const int lane = threadIdx.x & 63;
  int cnt = *qcount; if (cnt > QCAP) cnt = QCAP;
  if (w >= cnt) return;
  const int tok = queue[w];
  const float rn = inv_n[tok];
  const float* x = inp + (size_t)tok * FDIM;
  #pragma unroll
  for (int h = 0; h < 2; ++h) {
    float4 xv = *(const float4*)(x + h * 256 + lane * 4);
    float vv[4] = {xv.x, xv.y, xv.z, xv.w};
    ushort4 hs, lo;
    #pragma unroll
    for (int q = 0; q < 4; ++q) {
      float v = vv[q] * rn;
      unsigned short hb = f2bf(v);
      ((unsigned short*)&hs)[q] = hb;
      ((unsigned short*)&lo)[q] = f2bf(v - bf2f(hb));
    }
    const size_t e = (size_t)w * FDIM + h * 256 + lane * 4;
    *(ushort4*)(Qh + e) = hs;
    *(ushort4*)(Ql + e) = lo;
  }
}

// ------- level-2: full-row top-2 on split-S; fp64 pair-decide; write idx -------
__global__ __launch_bounds__(256) void refine2_k(
    const int* __restrict__ queue, const int* __restrict__ qcount,
    const float* __restrict__ Sref, const float* __restrict__ inp,
    const float* __restrict__ mem, int* __restrict__ idx) {
  const int w = blockIdx.x * 4 + (threadIdx.x >> 6);
  const int lane = threadIdx.x & 63;
  int cnt = *qcount; if (cnt > QCAP) cnt = QCAP;
  if (w >= cnt) return;
  const int tok = queue[w];
  const float* srow = Sref + (size_t)w * MDIM;
  float m1 = -3.4e38f, m2 = -3.4e38f;
  int i1 = 0x7fffffff, i2 = 0x7fffffff;
  #pragma unroll
  for (int i = 0; i < 8; ++i) {
    const float4 vv = *(const float4*)(srow + i * 256 + lane * 4);
    const float xs[4] = {vv.x, vv.y, vv.z, vv.w};
    #pragma unroll
    for (int q = 0; q < 4; ++q) {
      const float x = xs[q];
      const int ii = i * 256 + lane * 4 + q;
      if (x > m1 || (x == m1 && ii < i1)) { m2 = m1; i2 = i1; m1 = x; i1 = ii; }
      else if (x > m2 || (x == m2 && ii < i2)) { m2 = x; i2 = ii; }
    }
  }
  #pragma unroll
  for (int off = 1; off < 64; off <<= 1) {
    const float n1 = __shfl_xor(m1, off), n2 = __shfl_xor(m2, off);
    const int j1 = __shfl_xor(i1, off), j2 = __shfl_xor(i2, off);
    if (n1 > m1 || (n1 == m1 && j1 < i1)) {
      if (m1 > n2 || (m1 == n2 && i1 < j2)) { m2 = m1; i2 = i1; }
      else { m2 = n2; i2 = j2; }
      m1 = n1; i1 = j1;
    } else if (n1 > m2 || (n1 == m2 && j1 < i2)) { m2 = n1; i2 = j1; }
  }
  int pick = i1;
  if (m1 - m2 < TAU_SP) {
    const int a = (i1 < i2) ? i1 : i2, b = (i1 < i2) ? i2 : i1;
    const float* x = inp + (size_t)tok * FDIM;
    const float* ma = mem + (size_t)a * FDIM;
    const float* mb = mem + (size_t)b * FDIM;
    double da = 0, db = 0, na = 0, nb = 0;
    #pragma unroll
    for (int j = 0; j < 8; ++j) {
      const int e = lane * 8 + j;
      const double xv = x[e], av = ma[e], bv = mb[e];
      da += xv * av; na += av * av;
      db += xv * bv; nb += bv * bv;
    }
    #pragma unroll
    for (int off = 1; off < 64; off <<= 1) {
      da += __shfl_xor(da, off); na += __shfl_xor(na, off);
      db += __shfl_xor(db, off); nb += __shfl_xor(nb, off);
    }
    const double d1 = da / sqrt(fmax(na, 1e-12));
    const double d2 = db / sqrt(fmax(nb, 1e-12));
    if (d2 > d1) pick = b;
    else pick = a;
  }
  if (lane == 0) idx[tok] = pick;
}

// ------- deterministic segment-sum: one block per code, no atomics -------
__global__ __launch_bounds__(256) void segsum_k(
    const int* __restrict__ idx, const float* __restrict__ inp,
    const float* __restrict__ inv_n, float* __restrict__ updates) {
  __shared__ int lst[256];
  __shared__ int lcnt;
  const int m = blockIdx.x;
  const int t = threadIdx.x;
  float a0 = 0.f, a1 = 0.f;
  for (int base = 0; base < N_TOK; base += 4096) {
    if (t == 0) lcnt = 0;
    __syncthreads();
    #pragma unroll
    for (int u = 0; u < 4; ++u) {
      const int off4 = (u * 256 + t) * 4;
      const int4 v = *(const int4*)&idx[base + off4];
      if (v.x == m) { int p = atomicAdd(&lcnt, 1); if (p < 256) lst[p] = base + off4 + 0; }
      if (v.y == m) { int p = atomicAdd(&lcnt, 1); if (p < 256) lst[p] = base + off4 + 1; }
      if (v.z == m) { int p = atomicAdd(&lcnt, 1); if (p < 256) lst[p] = base + off4 + 2; }
      if (v.w == m) { int p = atomicAdd(&lcnt, 1); if (p < 256) lst[p] = base + off4 + 3; }
    }
    __syncthreads();
    int c = lcnt; if (c > 256) c = 256;
    if (t == 0 && c > 1) {
      for (int i = 1; i < c; ++i) {
        int key = lst[i], j = i - 1;
        while (j >= 0 && lst[j] > key) { lst[j + 1] = lst[j]; --j; }
        lst[j + 1] = key;
      }
    }
    __syncthreads();
    for (int i = 0; i < c; ++i) {
      const int tok = lst[i];
      const float rn = inv_n[tok];
      const float2 xv = *(const float2*)&inp[(size_t)tok * FDIM + t * 2];
      a0 += xv.x * rn; a1 += xv.y * rn;
    }
    __syncthreads();
  }
  *(float2*)&updates[(size_t)m * FDIM + t * 2] = make_float2(a0, a1);
}

// ---------------- final blend (fp32 out) ----------------
__global__ __launch_bounds__(256) void final_update_k(
    const float* __restrict__ mem, const float* __restrict__ upd,
    float* __restrict__ out) {
  const size_t i = ((size_t)blockIdx.x * 256 + threadIdx.x) * 4;
  float4 m = *(const float4*)(mem + i);
  float4 u = *(const float4*)(upd + i);
  float4 r;
  r.x = m.x * 0.9f + u.x * 0.1f;
  r.y = m.y * 0.9f + u.y * 0.1f;
  r.z = m.z * 0.9f + u.z * 0.1f;
  r.w = m.w * 0.9f + u.w * 0.1f;
  *(float4*)(out + i) = r;
}

extern "C" void kernel_launch(void* const* d_in, const int* in_sizes, int n_in,
                              void* d_out, int out_size, void* d_ws, size_t ws_size,
                              hipStream_t stream) {
  const float* inputs = (const float*)d_in[0];
  const float* memory = (const float*)d_in[1];
  if (n_in >= 2 && in_sizes[0] != N_TOK * FDIM) {  // order guard
    inputs = (const float*)d_in[1];
    memory = (const float*)d_in[0];
  }
  float* out_mu = (float*)d_out;                       // [N][F] fp32
  float* out_um = out_mu + (size_t)N_TOK * FDIM;       // [M][F] fp32

  char* base = (char*)d_ws;
  size_t off = 0;
  auto take = [&](size_t bytes) -> char* {
    char* p = base + off;
    off = (off + bytes + 255) & ~(size_t)255;
    return p;
  };
  unsigned short* Bh = (unsigned short*)take((size_t)MDIM * FDIM * 2);
  unsigned short* Bl = (unsigned short*)take((size_t)MDIM * FDIM * 2);
  unsigned short* Bt = (unsigned short*)take((size_t)MDIM * FDIM * 2);
  float* inv_n = (float*)take((size_t)N_TOK * 4);
  float* updates = (float*)take((size_t)MDIM * FDIM * 4);
  int* idx = (int*)take((size_t)N_TOK * 4);
  int* queue = (int*)take((size_t)QCAP * 4);
  int* qcount = (int*)take(256);
  unsigned short* Qh = (unsigned short*)take((size_t)QCAP * FDIM * 2);
  unsigned short* Ql = (unsigned short*)take((size_t)QCAP * FDIM * 2);
  float* Sref = (float*)take((size_t)QCAP * MDIM * 4);
  const size_t fixed = off;

  // per-token: Ah 1024 + P 4096 + sidecar 16*(4+8+8)=320 + rowinv 4
  int chunkT = 65536;  // single pass if ws allows
  while (chunkT > 128 && fixed + (size_t)chunkT * 5700 + 8192 > ws_size)
    chunkT >>= 1;
  if (fixed + (size_t)chunkT * 5700 + 8192 > ws_size) return;  // ws too small

  unsigned short* Ah = (unsigned short*)take((size_t)chunkT * FDIM * 2);
  unsigned short* Pbuf = (unsigned short*)take((size_t)chunkT * MDIM * 2);
  float* ssum = (float*)take((size_t)chunkT * 16 * 4);
  unsigned long long* sk1 = (unsigned long long*)take((size_t)chunkT * 16 * 8);
  unsigned long long* sk2 = (unsigned long long*)take((size_t)chunkT * 16 * 8);
  float* rowinv = (float*)take((size_t)chunkT * 4);

  zero_k<<<1, 64, 0, stream>>>(qcount);
  prep_memory_k<<<MDIM, 64, 0, stream>>>(memory, Bh, Bl);
  transpose_k<<<dim3(MDIM / 32, FDIM / 32), 256, 0, stream>>>(Bh, Bt);

  const int nby = chunkT / 128;
  for (int baseRow = 0; baseRow < N_TOK; baseRow += chunkT) {
    prep_a_k<<<chunkT / 4, 256, 0, stream>>>(inputs, inv_n, Ah, baseRow);
    // GEMM1 + exp + sidecar (S never hits HBM)
    gemm_bt_k<1, false, true><<<16 * nby, 256, 0, stream>>>(
        Ah, nullptr, Bh, nullptr, (void*)Pbuf, MDIM, FDIM, 4, nullptr,
        ssum, sk1, sk2, nullptr);
    rowstat_k<<<chunkT / 16, 256, 0, stream>>>(
        ssum, sk1, sk2, idx, rowinv, queue, qcount, baseRow);
    // GEMM2: out = (P * Bt^T) * rowinv
    gemm_bt_k<2, false, true><<<4 * nby, 256, 0, stream>>>(
        Pbuf, nullptr, Bt, nullptr, (void*)(out_mu + (size_t)baseRow * FDIM),
        FDIM, MDIM, 2, nullptr, nullptr, nullptr, nullptr, rowinv);
  }
  // two-level argmax refine: gather ambiguous rows, split-GEMM, decide idx
  gather_prep_k<<<QCAP / 4, 256, 0, stream>>>(queue, qcount, inputs, inv_n, Qh, Ql);
  gemm_bt_k<0, true, false><<<16 * (QCAP / 128), 256, 0, stream>>>(
      Qh, Ql, Bh, Bl, (void*)Sref, MDIM, FDIM, 4, qcount,
      nullptr, nullptr, nullptr, nullptr);
  refine2_k<<<QCAP / 4, 256, 0, stream>>>(queue, qcount, Sref, inputs, memory, idx);
  // deterministic segment-sum (no atomics), then blend
  segsum_k<<<MDIM, 256, 0, stream>>>(idx, inputs, inv_n, updates);
  final_update_k<<<(MDIM * FDIM / 4) / 256, 256, 0, stream>>>(memory, updates, out_um);
}

// Round 13
// 718.656 us; speedup vs baseline: 1.6695x; 1.0452x over previous
//
#include <hip/hip_runtime.h>
#include <stdint.h>

#define N_TOK   65536
#define MDIM    2048
#define FDIM    512
#define SCALE_F 10.0f
#define TAU_BF  1.2e-3f   // level-1: bf16-S ambiguity (~9 sigma)
#define TAU_SP  2e-5f     // level-2: split-S ambiguity (~100 sigma)
#define QCAP    8192

typedef __attribute__((ext_vector_type(8))) unsigned short u16x8;
typedef __attribute__((ext_vector_type(4))) unsigned short u16x4;
typedef __attribute__((ext_vector_type(8))) __bf16 bf16x8;
typedef __attribute__((ext_vector_type(4))) float f32x4;

__device__ __forceinline__ unsigned short f2bf(float f) {
  unsigned int u = __builtin_bit_cast(unsigned int, f);
  u += 0x7fffu + ((u >> 16) & 1u);   // round-to-nearest-even
  return (unsigned short)(u >> 16);
}
__device__ __forceinline__ float bf2f(unsigned short b) {
  return __builtin_bit_cast(float, (unsigned int)b << 16);
}
__device__ __forceinline__ f32x4 mfma16(u16x8 a, u16x8 b, f32x4 c) {
  return __builtin_amdgcn_mfma_f32_16x16x32_bf16(
      __builtin_bit_cast(bf16x8, a), __builtin_bit_cast(bf16x8, b), c, 0, 0, 0);
}
__device__ __forceinline__ void gload16(const unsigned short* g, unsigned short* l) {
  __builtin_amdgcn_global_load_lds(
      (const __attribute__((address_space(1))) unsigned int*)g,
      (__attribute__((address_space(3))) unsigned int*)l,
      16, 0, 0);
}
// order-preserving float->u32; tie -> smaller col wins (np.argmax)
__device__ __forceinline__ unsigned long long packkey(float x, int col) {
  unsigned u = __builtin_bit_cast(unsigned, x);
  u = (u & 0x80000000u) ? ~u : (u | 0x80000000u);
  return ((unsigned long long)u << 32) | (unsigned)(2048 - col);
}
__device__ __forceinline__ float unpackval(unsigned long long k) {
  unsigned u = (unsigned)(k >> 32);
  u = (u & 0x80000000u) ? (u & 0x7fffffffu) : ~u;
  return __builtin_bit_cast(float, u);
}
__device__ __forceinline__ int unpackcol(unsigned long long k) {
  return 2048 - (int)(k & 0xffffffffu);
}
__device__ __forceinline__ void merge2(unsigned long long& k1, unsigned long long& k2,
                                       unsigned long long o1, unsigned long long o2) {
  if (o1 > k1) { k2 = (k1 > o2) ? k1 : o2; k1 = o1; }
  else if (o1 > k2) { k2 = o1; }
}

// ---------------- zero queue counter ----------------
__global__ __launch_bounds__(64) void zero_k(int* __restrict__ qcount) {
  if (threadIdx.x == 0) *qcount = 0;
}

// ---------------- memory_norm -> bf16 hi/lo ----------------
__global__ __launch_bounds__(64) void prep_memory_k(
    const float* __restrict__ mem, unsigned short* __restrict__ Bh,
    unsigned short* __restrict__ Bl) {
  const int m = blockIdx.x;
  const int lane = threadIdx.x;
  const float* row = mem + (size_t)m * FDIM;
  float4 a = *(const float4*)(row + lane * 4);
  float4 b = *(const float4*)(row + 256 + lane * 4);
  float s = a.x * a.x + a.y * a.y + a.z * a.z + a.w * a.w +
            b.x * b.x + b.y * b.y + b.z * b.z + b.w * b.w;
  #pragma unroll
  for (int off = 1; off < 64; off <<= 1) s += __shfl_xor(s, off);
  const float rn = 1.0f / sqrtf(fmaxf(s, 1e-12f));
  float v[8] = {a.x, a.y, a.z, a.w, b.x, b.y, b.z, b.w};
  #pragma unroll
  for (int h = 0; h < 2; ++h) {
    ushort4 hs, lo;
    #pragma unroll
    for (int q = 0; q < 4; ++q) {
      float x = v[h * 4 + q] * rn;
      unsigned short hb = f2bf(x);
      ((unsigned short*)&hs)[q] = hb;
      ((unsigned short*)&lo)[q] = f2bf(x - bf2f(hb));
    }
    const size_t e = (size_t)m * FDIM + h * 256 + lane * 4;
    *(ushort4*)(Bh + e) = hs;
    *(ushort4*)(Bl + e) = lo;
  }
}

// ---------------- transpose Bh [M][F] -> Bt [F][M] ----------------
__global__ __launch_bounds__(256) void transpose_k(
    const unsigned short* __restrict__ Bh, unsigned short* __restrict__ Bt) {
  __shared__ unsigned short t[32][33];
  const int m0 = blockIdx.x * 32, f0 = blockIdx.y * 32;
  const int tx = threadIdx.x & 31, ty = threadIdx.x >> 5;
  #pragma unroll
  for (int r = ty; r < 32; r += 8)
    t[r][tx] = Bh[(size_t)(m0 + r) * FDIM + f0 + tx];
  __syncthreads();
  #pragma unroll
  for (int r = ty; r < 32; r += 8)
    Bt[(size_t)(f0 + r) * MDIM + m0 + tx] = t[tx][r];
}

// ------- fused: input row inv-norm + inputs_norm -> bf16 (one pass) -------
__global__ __launch_bounds__(256) void prep_a_k(
    const float* __restrict__ inp, float* __restrict__ inv_n,
    unsigned short* __restrict__ Ah, int baseRow) {
  const int r = blockIdx.x * 4 + (threadIdx.x >> 6);   // chunk-local row
  const int lane = threadIdx.x & 63;
  const int grow = baseRow + r;
  const float* x = inp + (size_t)grow * FDIM;
  float4 a = *(const float4*)(x + lane * 4);
  float4 b = *(const float4*)(x + 256 + lane * 4);
  float s = a.x * a.x + a.y * a.y + a.z * a.z + a.w * a.w +
            b.x * b.x + b.y * b.y + b.z * b.z + b.w * b.w;
  #pragma unroll
  for (int off = 1; off < 64; off <<= 1) s += __shfl_xor(s, off);
  const float rn = 1.0f / sqrtf(fmaxf(s, 1e-12f));
  if (lane == 0) inv_n[grow] = rn;
  ushort4 h0, h1;
  h0.x = f2bf(a.x * rn); h0.y = f2bf(a.y * rn);
  h0.z = f2bf(a.z * rn); h0.w = f2bf(a.w * rn);
  h1.x = f2bf(b.x * rn); h1.y = f2bf(b.y * rn);
  h1.z = f2bf(b.z * rn); h1.w = f2bf(b.w * rn);
  *(ushort4*)(Ah + (size_t)r * FDIM + lane * 4) = h0;
  *(ushort4*)(Ah + (size_t)r * FDIM + 256 + lane * 4) = h1;
}

// ============ 8-phase 256x256 GEMM: C = A * B^T (B row-major [N][K]) ============
// 512 threads (8 waves, 2M x 4N), BK=64, 2 K-tiles/iter, 8 phases/iter.
// LDS 128KB: 2 buffers x { A 2x(128x64), B 2x(128x64) } bf16, XOR slot-swizzle
// (phys16Bslot = logslot ^ (row&7)); linear gload dest + inverse-swz source.
// Staging units scheduled into the phase where their region just died (WAR-safe
// via barrier-B); counted vmcnt(7) only at phases 0/4 (vmcnt(0) at last P4).
// MODE 1: P=bf16(exp(10*s)) + sidecar(row,bx) esum/top2.  MODE 2: C=acc*rowinv.
template <int MODE>
__global__ __launch_bounds__(512) void gemm8p_k(
    const unsigned short* __restrict__ Am, const unsigned short* __restrict__ Bm,
    void* __restrict__ Cv, int N, int K, int nbxLog2,
    float* __restrict__ ssum, unsigned long long* __restrict__ sk1,
    unsigned long long* __restrict__ sk2, const float* __restrict__ rowinv) {
  __shared__ alignas(16) char smem[131072];
  int wg = blockIdx.x;
  { const int q = gridDim.x >> 3; wg = (wg & 7) * q + (wg >> 3); }  // XCD swizzle
  const int bx = wg & ((1 << nbxLog2) - 1);
  const int by = wg >> nbxLog2;
  const int m0 = by * 256, n0 = bx * 256;
  const int tid = threadIdx.x;
  const int lane = tid & 63, wid = tid >> 6;
  const int wm = wid >> 2, wn = wid & 3;
  const int lr = lane & 15, ls = lane >> 4;
  const int c16 = (lane & 7) ^ (lane >> 3);   // inverse-swizzled source slot
  const int lrow8 = lane >> 3;

  f32x4 acc[8][4] = {};
  u16x8 bF[4][2];

  const int NT = K >> 6;        // K-tiles (BK=64)
  const int niter = NT >> 1;

  auto stageB = [&](int t, int half) {   // 2 chunks/wave (16KB unit)
    char* dst0 = smem + (t & 1) * 65536 + 32768 + half * 16384;
    #pragma unroll
    for (int c = 0; c < 2; ++c) {
      const int R = (wid * 2 + c) * 8;
      const int rg = n0 + half * 128 + R + lrow8;
      gload16(Bm + (size_t)rg * K + t * 64 + c16 * 8,
              (unsigned short*)(dst0 + R * 128));
    }
  };
  auto stageA = [&](int t, int q) {      // 1 chunk/wave (8KB unit, rows q*32..+32)
    const int half = wid >> 2;
    const int R = q * 32 + (wid & 3) * 8;
    char* dst = smem + (t & 1) * 65536 + half * 16384 + R * 128;
    const int rg = m0 + half * 128 + R + lrow8;
    gload16(Am + (size_t)rg * K + t * 64 + c16 * 8, (unsigned short*)dst);
  };
  auto ldsA = [&](int b, int rl, int ks) -> u16x8 {
    const int p = (ks * 4 + ls) ^ (rl & 7);
    return *(const u16x8*)(smem + b * 65536 + wm * 16384 + rl * 128 + p * 16);
  };
  auto ldsB = [&](int b, int rlb, int ks) -> u16x8 {
    const int half = rlb >> 7, rl = rlb & 127;
    const int p = (ks * 4 + ls) ^ (rl & 7);
    return *(const u16x8*)(smem + b * 65536 + 32768 + half * 16384 + rl * 128 + p * 16);
  };

  // prologue: tile0 full (8 loads), tile1 minus Au3 (7 loads)
  stageB(0, 0); stageB(0, 1);
  stageA(0, 0); stageA(0, 1); stageA(0, 2); stageA(0, 3);
  stageB(1, 0); stageB(1, 1);
  stageA(1, 0); stageA(1, 1); stageA(1, 2);

  for (int it = 0; it < niter; ++it) {
    const int T0 = 2 * it, T1 = T0 + 1;
    #pragma unroll
    for (int ph = 0; ph < 8; ++ph) {
      const int tb = (ph < 4) ? 0 : 1;       // buffer = tile parity
      const int ql = ph & 3;
      if (ql == 0) {
        if (ph == 4 && it == niter - 1)
          asm volatile("s_waitcnt vmcnt(0)" ::: "memory");  // tail: no trailing loads
        else
          asm volatile("s_waitcnt vmcnt(7)" ::: "memory");  // tile's 8 chunks landed
        __builtin_amdgcn_sched_barrier(0);
        __builtin_amdgcn_s_barrier();
        #pragma unroll
        for (int nj = 0; nj < 4; ++nj)
          #pragma unroll
          for (int ks = 0; ks < 2; ++ks)
            bF[nj][ks] = ldsB(tb, wn * 64 + nj * 16 + lr, ks);
      } else {
        __builtin_amdgcn_s_barrier();
      }
      u16x8 aF[2][2];
      #pragma unroll
      for (int di = 0; di < 2; ++di)
        #pragma unroll
        for (int ks = 0; ks < 2; ++ks)
          aF[di][ks] = ldsA(tb, ql * 32 + di * 16 + lr, ks);
      // staging schedule (region died last phase -> safe to overwrite now)
      if (ph == 0) { if (T1 < NT) stageA(T1, 3); }
      if (ph == 1) { if (T0 + 2 < NT) stageB(T0 + 2, 0); }
      if (ph == 2) { if (T0 + 2 < NT) { stageB(T0 + 2, 1); stageA(T0 + 2, 0); } }
      if (ph == 3) { if (T0 + 2 < NT) { stageA(T0 + 2, 1); stageA(T0 + 2, 2); } }
      if (ph == 4) { if (T0 + 2 < NT) stageA(T0 + 2, 3); }
      if (ph == 5) { if (T1 + 2 < NT) stageB(T1 + 2, 0); }
      if (ph == 6) { if (T1 + 2 < NT) { stageB(T1 + 2, 1); stageA(T1 + 2, 0); } }
      if (ph == 7) { if (T1 + 2 < NT) { stageA(T1 + 2, 1); stageA(T1 + 2, 2); } }
      __builtin_amdgcn_s_setprio(1);
      #pragma unroll
      for (int di = 0; di < 2; ++di)
        #pragma unroll
        for (int nj = 0; nj < 4; ++nj)
          #pragma unroll
          for (int ks = 0; ks < 2; ++ks)
            acc[ql * 2 + di][nj] = mfma16(aF[di][ks], bF[nj][ks], acc[ql * 2 + di][nj]);
      __builtin_amdgcn_s_setprio(0);
      __builtin_amdgcn_s_barrier();          // barrier-B: region discipline
    }
  }

  if constexpr (MODE == 1) {
    asm volatile("s_waitcnt vmcnt(0)" ::: "memory");   // drain before LDS reuse
    __builtin_amdgcn_sched_barrier(0);
    __builtin_amdgcn_s_barrier();
    unsigned short* P = (unsigned short*)Cv;
    float* sc = (float*)smem;                 // scratch [32][260] f32
    #pragma unroll
    for (int g = 0; g < 8; ++g) {
      if ((wid >> 2) == (g >> 2)) {           // 4 waves dump rows [g*32, g*32+32)
        const int di0 = (g & 3) * 2;
        #pragma unroll
        for (int di = 0; di < 2; ++di)
          #pragma unroll
          for (int nj = 0; nj < 4; ++nj)
            #pragma unroll
            for (int q = 0; q < 4; ++q)
              sc[(di * 16 + ls * 4 + q) * 260 + wn * 64 + nj * 16 + lr] =
                  acc[di0 + di][nj][q];
      }
      __syncthreads();
      {
        const int r = tid >> 4, cs = tid & 15;   // 32 rows x 16 col-slots
        const int grow = m0 + g * 32 + r;
        float esum = 0.f, m1v = -3.4e38f, m2v = -3.4e38f;
        int c1 = 0;
        unsigned short pk[16];
        #pragma unroll
        for (int k = 0; k < 4; ++k) {
          const f32x4 v = *(const f32x4*)&sc[r * 260 + cs * 16 + k * 4];
          #pragma unroll
          for (int e = 0; e < 4; ++e) {
            const float s = v[e];
            const int col = n0 + cs * 16 + k * 4 + e;
            if (s > m1v) { m2v = m1v; m1v = s; c1 = col; }
            else if (s > m2v) m2v = s;
            const float ex = __expf(SCALE_F * s);
            esum += ex;
            pk[k * 4 + e] = f2bf(ex);
          }
        }
        *(u16x8*)&P[(size_t)grow * N + n0 + cs * 16] = *(u16x8*)&pk[0];
        *(u16x8*)&P[(size_t)grow * N + n0 + cs * 16 + 8] = *(u16x8*)&pk[8];
        unsigned long long k1 = packkey(m1v, c1);
        unsigned long long k2 = packkey(m2v, 2047);
        #pragma unroll
        for (int off = 1; off < 16; off <<= 1) {   // merge 16 threads of the row
          const unsigned long long o1 = __shfl_xor(k1, off);
          const unsigned long long o2 = __shfl_xor(k2, off);
          esum += __shfl_xor(esum, off);
          merge2(k1, k2, o1, o2);
        }
        if (cs == 0) {
          const size_t sp = (size_t)grow * 8 + bx;
          ssum[sp] = esum; sk1[sp] = k1; sk2[sp] = k2;
        }
      }
      __syncthreads();
    }
  } else {
    float* C = (float*)Cv;
    #pragma unroll
    for (int mi = 0; mi < 8; ++mi) {
      const int rbase = m0 + wm * 128 + mi * 16 + ls * 4;
      #pragma unroll
      for (int q = 0; q < 4; ++q) {
        const float ri = rowinv[rbase + q];
        #pragma unroll
        for (int nj = 0; nj < 4; ++nj) {
          const int col = n0 + wn * 64 + nj * 16 + lr;
          C[(size_t)(rbase + q) * N + col] = acc[mi][nj][q] * ri;
        }
      }
    }
  }
}

// ---- refine split-GEMM (proven 128x128 dbuf kernel, hi/lo compensation) ----
__global__ __launch_bounds__(256) void gemm_ref_k(
    const unsigned short* __restrict__ Ah, const unsigned short* __restrict__ Al,
    const unsigned short* __restrict__ Bh, const unsigned short* __restrict__ Bl,
    float* __restrict__ C, int N, int K, int nbxLog2,
    const int* __restrict__ qlimit) {
  const int wg = blockIdx.x;
  const int bx = wg & ((1 << nbxLog2) - 1);
  const int by = wg >> nbxLog2;
  const int m0 = by * 128, n0 = bx * 128;
  {
    int lim = *qlimit; if (lim > QCAP) lim = QCAP;
    lim = (lim + 127) & ~127;
    if (m0 >= lim) return;
  }
  constexpr int BUF_B = 4 * 8192;
  __shared__ alignas(16) char smem[2 * BUF_B];

  const int tid = threadIdx.x;
  const int lane = tid & 63, wave = tid >> 6;
  const int wr = wave >> 1, wc = wave & 1;
  const int lr = lane & 15, ls = lane >> 4;

  f32x4 acc[4][4] = {};

  const int row0 = wave * 32 + (lane >> 2);
  const int row1 = row0 + 16;
  const int ce = (lane & 3) * 8;
  const unsigned short* gA0 = Ah + (size_t)(m0 + row0) * K + ce;
  const unsigned short* gA1 = Ah + (size_t)(m0 + row1) * K + ce;
  const unsigned short* gB0 = Bh + (size_t)(n0 + row0) * K + ce;
  const unsigned short* gB1 = Bh + (size_t)(n0 + row1) * K + ce;
  const unsigned short* gAl0 = Al + (size_t)(m0 + row0) * K + ce;
  const unsigned short* gAl1 = Al + (size_t)(m0 + row1) * K + ce;
  const unsigned short* gBl0 = Bl + (size_t)(n0 + row0) * K + ce;
  const unsigned short* gBl1 = Bl + (size_t)(n0 + row1) * K + ce;

  auto stage = [&](int buf) {
    char* sb = smem + buf * BUF_B;
    unsigned short* bAh = (unsigned short*)sb;
    unsigned short* bBh = (unsigned short*)(sb + 8192);
    unsigned short* bAl = (unsigned short*)(sb + 16384);
    unsigned short* bBl = (unsigned short*)(sb + 24576);
    gload16(gA0, &bAh[wave * 1024]); gload16(gA1, &bAh[wave * 1024 + 512]);
    gload16(gB0, &bBh[wave * 1024]); gload16(gB1, &bBh[wave * 1024 + 512]);
    gload16(gAl0, &bAl[wave * 1024]); gload16(gAl1, &bAl[wave * 1024 + 512]);
    gload16(gBl0, &bBl[wave * 1024]); gload16(gBl1, &bBl[wave * 1024 + 512]);
    gA0 += 32; gA1 += 32; gB0 += 32; gB1 += 32;
    gAl0 += 32; gAl1 += 32; gBl0 += 32; gBl1 += 32;
  };

  const int nk = K >> 5;
  stage(0);
  __syncthreads();
  for (int ks = 0; ks < nk; ++ks) {
    const int cur = ks & 1;
    if (ks + 1 < nk) stage(cur ^ 1);
    const char* sb = smem + cur * BUF_B;
    u16x8 fa[4], fb[4], fal[4], fbl[4];
    #pragma unroll
    for (int i = 0; i < 4; ++i) {
      const int ra = (wr * 64 + i * 16 + lr) * 32 + ls * 8;
      const int rb = (wc * 64 + i * 16 + lr) * 32 + ls * 8;
      fa[i] = *(const u16x8*)&((const unsigned short*)sb)[ra];
      fb[i] = *(const u16x8*)&((const unsigned short*)(sb + 8192))[rb];
      fal[i] = *(const u16x8*)&((const unsigned short*)(sb + 16384))[ra];
      fbl[i] = *(const u16x8*)&((const unsigned short*)(sb + 24576))[rb];
    }
    #pragma unroll
    for (int i = 0; i < 4; ++i)
      #pragma unroll
      for (int j = 0; j < 4; ++j) {
        acc[i][j] = mfma16(fa[i], fb[j], acc[i][j]);
        acc[i][j] = mfma16(fal[i], fb[j], acc[i][j]);
        acc[i][j] = mfma16(fa[i], fbl[j], acc[i][j]);
      }
    __syncthreads();
  }

  #pragma unroll
  for (int i = 0; i < 4; ++i) {
    const int rrow = m0 + wr * 64 + i * 16 + ls * 4;
    #pragma unroll
    for (int j = 0; j < 4; ++j) {
      const int col = n0 + wc * 64 + j * 16 + lr;
      #pragma unroll
      for (int q = 0; q < 4; ++q)
        C[(size_t)(rrow + q) * N + col] = acc[i][j][q];
    }
  }
}

// ------- merge 8 sidecar partials per row: idx, rowinv, queue -------
__global__ __launch_bounds__(256) void rowstat_k(
    const float* __restrict__ ssum, const unsigned long long* __restrict__ sk1,
    const unsigned long long* __restrict__ sk2, int* __restrict__ idx,
    float* __restrict__ rowinv, int* __restrict__ queue,
    int* __restrict__ qcount, int baseRow) {
  const int row = blockIdx.x * 32 + (threadIdx.x >> 3);
  const int p = threadIdx.x & 7;
  const size_t sp = (size_t)row * 8 + p;
  float sum = ssum[sp];
  unsigned long long k1 = sk1[sp], k2 = sk2[sp];
  #pragma unroll
  for (int off = 1; off < 8; off <<= 1) {
    const unsigned long long o1 = __shfl_xor(k1, off);
    const unsigned long long o2 = __shfl_xor(k2, off);
    sum += __shfl_xor(sum, off);
    merge2(k1, k2, o1, o2);
  }
  if (p == 0) {
    const int tok = baseRow + row;
    idx[tok] = unpackcol(k1);
    rowinv[row] = 1.0f / sum;
    if (unpackval(k1) - unpackval(k2) < TAU_BF) {
      int slot = atomicAdd(qcount, 1);
      if (slot < QCAP) queue[slot] = tok;
    }
  }
}

// ------- gather queued tokens' normalized rows -> compact hi/lo matrix -------
__global__ __launch_bounds__(256) void gather_prep_k(
    const int* __restrict__ queue, const int* __restrict__ qcount,
    const float* __restrict__ inp, const float* __restrict__ inv_n,
    unsigned short* __restrict__ Qh, unsigned short* __restrict__ Ql) {
  const int w = blockIdx.x * 4 + (threadIdx.x >> 6);
  const int lane = threadIdx.x & 63;
  int cnt = *qcount; if (cnt > QCAP) cnt = QCAP;
  if (w >= cnt) return;
  const int tok = queue[w];
  const float rn = inv_n[tok];
  const float* x = inp + (size_t)tok * FDIM;
  #pragma unroll
  for (int h = 0; h < 2; ++h) {
    float4 xv = *(const float4*)(x + h * 256 + lane * 4);
    float vv[4] = {xv.x, xv.y, xv.z, xv.w};
    ushort4 hs, lo;
    #pragma unroll
    for (int q = 0; q < 4; ++q) {
      float v = vv[q] * rn;
      unsigned short hb = f2bf(v);
      ((unsigned short*)&hs)[q] = hb;
      ((unsigned short*)&lo)[q] = f2bf(v - bf2f(hb));
    }
    const size_t e = (size_t)w * FDIM + h * 256 + lane * 4;
    *(ushort4*)(Qh + e) = hs;
    *(ushort4*)(Ql + e) = lo;
  }
}

// ------- level-2: full-row top-2 on split-S; fp64 pair-decide; write idx -------
__global__ __launch_bounds__(256) void refine2_k(
    const int* __restrict__ queue, const int* __restrict__ qcount,
    const float* __restrict__ Sref, const float* __restrict__ inp,
    const float* __restrict__ mem, int* __restrict__ idx) {
  const int w = blockIdx.x * 4 + (threadIdx.x >> 6);
  const int lane = threadIdx.x & 63;
  int cnt = *qcount; if (cnt > QCAP) cnt = QCAP;
  if (w >= cnt) return;
  const int tok = queue[w];
  const float* srow = Sref + (size_t)w * MDIM;
  float m1 = -3.4e38f, m2 = -3.4e38f;
  int i1 = 0x7fffffff, i2 = 0x7fffffff;
  #pragma unroll
  for (int i = 0; i < 8; ++i) {
    const float4 vv = *(const float4*)(srow + i * 256 + lane * 4);
    const float xs[4] = {vv.x, vv.y, vv.z, vv.w};
    #pragma unroll
    for (int q = 0; q < 4; ++q) {
      const float x = xs[q];
      const int ii = i * 256 + lane * 4 + q;
      if (x > m1 || (x == m1 && ii < i1)) { m2 = m1; i2 = i1; m1 = x; i1 = ii; }
      else if (x > m2 || (x == m2 && ii < i2)) { m2 = x; i2 = ii; }
    }
  }
  #pragma unroll
  for (int off = 1; off < 64; off <<= 1) {
    const float n1 = __shfl_xor(m1, off), n2 = __shfl_xor(m2, off);
    const int j1 = __shfl_xor(i1, off), j2 = __shfl_xor(i2, off);
    if (n1 > m1 || (n1 == m1 && j1 < i1)) {
      if (m1 > n2 || (m1 == n2 && i1 < j2)) { m2 = m1; i2 = i1; }
      else { m2 = n2; i2 = j2; }
      m1 = n1; i1 = j1;
    } else if (n1 > m2 || (n1 == m2 && j1 < i2)) { m2 = n1; i2 = j1; }
  }
  int pick = i1;
  if (m1 - m2 < TAU_SP) {
    const int a = (i1 < i2) ? i1 : i2, b = (i1 < i2) ? i2 : i1;
    const float* x = inp + (size_t)tok * FDIM;
    const float* ma = mem + (size_t)a * FDIM;
    const float* mb = mem + (size_t)b * FDIM;
    double da = 0, db = 0, na = 0, nb = 0;
    #pragma unroll
    for (int j = 0; j < 8; ++j) {
      const int e = lane * 8 + j;
      const double xv = x[e], av = ma[e], bv = mb[e];
      da += xv * av; na += av * av;
      db += xv * bv; nb += bv * bv;
    }
    #pragma unroll
    for (int off = 1; off < 64; off <<= 1) {
      da += __shfl_xor(da, off); na += __shfl_xor(na, off);
      db += __shfl_xor(db, off); nb += __shfl_xor(nb, off);
    }
    const double d1 = da / sqrt(fmax(na, 1e-12));
    const double d2 = db / sqrt(fmax(nb, 1e-12));
    if (d2 > d1) pick = b;
    else pick = a;
  }
  if (lane == 0) idx[tok] = pick;
}

// ------- deterministic segment-sum: one block per code, no atomics -------
__global__ __launch_bounds__(256) void segsum_k(
    const int* __restrict__ idx, const float* __restrict__ inp,
    const float* __restrict__ inv_n, float* __restrict__ updates) {
  __shared__ int lst[256];
  __shared__ int lcnt;
  const int m = blockIdx.x;
  const int t = threadIdx.x;
  float a0 = 0.f, a1 = 0.f;
  for (int base = 0; base < N_TOK; base += 4096) {
    if (t == 0) lcnt = 0;
    __syncthreads();
    #pragma unroll
    for (int u = 0; u < 4; ++u) {
      const int off4 = (u * 256 + t) * 4;
      const int4 v = *(const int4*)&idx[base + off4];
      if (v.x == m) { int p = atomicAdd(&lcnt, 1); if (p < 256) lst[p] = base + off4 + 0; }
      if (v.y == m) { int p = atomicAdd(&lcnt, 1); if (p < 256) lst[p] = base + off4 + 1; }
      if (v.z == m) { int p = atomicAdd(&lcnt, 1); if (p < 256) lst[p] = base + off4 + 2; }
      if (v.w == m) { int p = atomicAdd(&lcnt, 1); if (p < 256) lst[p] = base + off4 + 3; }
    }
    __syncthreads();
    int c = lcnt; if (c > 256) c = 256;
    if (t == 0 && c > 1) {
      for (int i = 1; i < c; ++i) {
        int key = lst[i], j = i - 1;
        while (j >= 0 && lst[j] > key) { lst[j + 1] = lst[j]; --j; }
        lst[j + 1] = key;
      }
    }
    __syncthreads();
    for (int i = 0; i < c; ++i) {
      const int tok = lst[i];
      const float rn = inv_n[tok];
      const float2 xv = *(const float2*)&inp[(size_t)tok * FDIM + t * 2];
      a0 += xv.x * rn; a1 += xv.y * rn;
    }
    __syncthreads();
  }
  *(float2*)&updates[(size_t)m * FDIM + t * 2] = make_float2(a0, a1);
}

// ---------------- final blend (fp32 out) ----------------
__global__ __launch_bounds__(256) void final_update_k(
    const float* __restrict__ mem, const float* __restrict__ upd,
    float* __restrict__ out) {
  const size_t i = ((size_t)blockIdx.x * 256 + threadIdx.x) * 4;
  float4 m = *(const float4*)(mem + i);
  float4 u = *(const float4*)(upd + i);
  float4 r;
  r.x = m.x * 0.9f + u.x * 0.1f;
  r.y = m.y * 0.9f + u.y * 0.1f;
  r.z = m.z * 0.9f + u.z * 0.1f;
  r.w = m.w * 0.9f + u.w * 0.1f;
  *(float4*)(out + i) = r;
}

extern "C" void kernel_launch(void* const* d_in, const int* in_sizes, int n_in,
                              void* d_out, int out_size, void* d_ws, size_t ws_size,
                              hipStream_t stream) {
  const float* inputs = (const float*)d_in[0];
  const float* memory = (const float*)d_in[1];
  if (n_in >= 2 && in_sizes[0] != N_TOK * FDIM) {  // order guard
    inputs = (const float*)d_in[1];
    memory = (const float*)d_in[0];
  }
  float* out_mu = (float*)d_out;                       // [N][F] fp32
  float* out_um = out_mu + (size_t)N_TOK * FDIM;       // [M][F] fp32

  char* base = (char*)d_ws;
  size_t off = 0;
  auto take = [&](size_t bytes) -> char* {
    char* p = base + off;
    off = (off + bytes + 255) & ~(size_t)255;
    return p;
  };
  unsigned short* Bh = (unsigned short*)take((size_t)MDIM * FDIM * 2);
  unsigned short* Bl = (unsigned short*)take((size_t)MDIM * FDIM * 2);
  unsigned short* Bt = (unsigned short*)take((size_t)MDIM * FDIM * 2);
  float* inv_n = (float*)take((size_t)N_TOK * 4);
  float* updates = (float*)take((size_t)MDIM * FDIM * 4);
  int* idx = (int*)take((size_t)N_TOK * 4);
  int* queue = (int*)take((size_t)QCAP * 4);
  int* qcount = (int*)take(256);
  unsigned short* Qh = (unsigned short*)take((size_t)QCAP * FDIM * 2);
  unsigned short* Ql = (unsigned short*)take((size_t)QCAP * FDIM * 2);
  float* Sref = (float*)take((size_t)QCAP * MDIM * 4);
  const size_t fixed = off;

  // per-token: Ah 1024 + P 4096 + sidecar 8*(4+8+8)=160 + rowinv 4
  int chunkT = 65536;  // single pass if ws allows
  while (chunkT > 2048 && fixed + (size_t)chunkT * 5400 + 8192 > ws_size)
    chunkT >>= 1;
  if (fixed + (size_t)chunkT * 5400 + 8192 > ws_size) return;  // ws too small

  unsigned short* Ah = (unsigned short*)take((size_t)chunkT * FDIM * 2);
  unsigned short* Pbuf = (unsigned short*)take((size_t)chunkT * MDIM * 2);
  float* ssum = (float*)take((size_t)chunkT * 8 * 4);
  unsigned long long* sk1 = (unsigned long long*)take((size_t)chunkT * 8 * 8);
  unsigned long long* sk2 = (unsigned long long*)take((size_t)chunkT * 8 * 8);
  float* rowinv = (float*)take((size_t)chunkT * 4);

  zero_k<<<1, 64, 0, stream>>>(qcount);
  prep_memory_k<<<MDIM, 64, 0, stream>>>(memory, Bh, Bl);
  transpose_k<<<dim3(MDIM / 32, FDIM / 32), 256, 0, stream>>>(Bh, Bt);

  for (int baseRow = 0; baseRow < N_TOK; baseRow += chunkT) {
    prep_a_k<<<chunkT / 4, 256, 0, stream>>>(inputs, inv_n, Ah, baseRow);
    // GEMM1 (8-phase 256^2): P = bf16(exp(10*S)) + sidecar; S never hits HBM
    gemm8p_k<1><<<(chunkT / 256) * 8, 512, 0, stream>>>(
        Ah, Bh, (void*)Pbuf, MDIM, FDIM, 3, ssum, sk1, sk2, nullptr);
    rowstat_k<<<chunkT / 32, 256, 0, stream>>>(
        ssum, sk1, sk2, idx, rowinv, queue, qcount, baseRow);
    // GEMM2 (8-phase 256^2): out = (P * Bt^T) * rowinv
    gemm8p_k<2><<<(chunkT / 256) * 2, 512, 0, stream>>>(
        Pbuf, Bt, (void*)(out_mu + (size_t)baseRow * FDIM), FDIM, MDIM, 1,
        nullptr, nullptr, nullptr, rowinv);
  }
  // two-level argmax refine: gather ambiguous rows, split-GEMM, decide idx
  gather_prep_k<<<QCAP / 4, 256, 0, stream>>>(queue, qcount, inputs, inv_n, Qh, Ql);
  gemm_ref_k<<<16 * (QCAP / 128), 256, 0, stream>>>(
      Qh, Ql, Bh, Bl, Sref, MDIM, FDIM, 4, qcount);
  refine2_k<<<QCAP / 4, 256, 0, stream>>>(queue, qcount, Sref, inputs, memory, idx);
  // deterministic segment-sum (no atomics), then blend
  segsum_k<<<MDIM, 256, 0, stream>>>(idx, inputs, inv_n, updates);
  final_update_k<<<(MDIM * FDIM / 4) / 256, 256, 0, stream>>>(memory, updates, out_um);
}